// Round 5
// baseline (967.848 us; speedup 1.0000x reference)
//
#include <hip/hip_runtime.h>

typedef unsigned short ushort_t;
typedef unsigned int uint_t;

typedef __bf16 bf16x8 __attribute__((ext_vector_type(8)));
typedef float f32x4 __attribute__((ext_vector_type(4)));

#define NPTS (1 << 20)

// ---- ws layout (ushort units) ----
#define OFF_FLAG 0        // uint flag at ws[0..1]: 1 = inputs are bf16, 0 = fp32
#define OFF_B0   16
#define OFF_B1   272
#define OFF_B2   528
#define OFF_B3   784
#define OFF_BSIG 1040
#define OFF_BRGB 1041
#define OFF_W0   1056     // K=64 (47 padded), N=256: 32 tiles * 512
#define OFF_W1   17440    // K=256,N=256: 128 tiles * 512
#define OFF_W2   82976
#define OFF_W3   148512
#define OFF_WH   214048   // K=256,N=16 (rgb0,rgb1,rgb2,sig,0...): 8 tiles * 512
#define OFF_PL   218144   // transposed planes [plane][pos(16384)][rank(8)]

__device__ __forceinline__ float bf2f(ushort_t u) {
  union { uint_t i; float f; } c; c.i = ((uint_t)u) << 16; return c.f;
}
__device__ __forceinline__ ushort_t f2bf(float f) {
  union { float f; uint_t i; } c; c.f = f;
  uint_t x = c.i;
  return (ushort_t)((x + 0x7fffu + ((x >> 16) & 1u)) >> 16);
}
// dtype-branched scalar loads
__device__ __forceinline__ float ldf(const void* p, long i, int isbf) {
  return isbf ? bf2f(((const ushort_t*)p)[i]) : ((const float*)p)[i];
}
__device__ __forceinline__ ushort_t ldbf(const void* p, long i, int isbf) {
  return isbf ? ((const ushort_t*)p)[i] : f2bf(((const float*)p)[i]);
}
__device__ __forceinline__ void stf(void* p, long i, int isbf, float v) {
  if (isbf) ((ushort_t*)p)[i] = f2bf(v);
  else      ((float*)p)[i] = v;
}

// XOR-swizzled LDS activation address (row-major 128 x 256 bf16, 16B-group swizzle)
__device__ __forceinline__ int act_addr(int row, int k) {
  return row * 256 + ((((k >> 3) ^ (row & 31)) << 3) | (k & 7));
}

// ------------------------------------------------------------------
// sniff: decide whether inputs are stored as bf16 or fp32.
// ------------------------------------------------------------------
__global__ void sniff_dtype(const void* __restrict__ f, ushort_t* __restrict__ ws) {
  __shared__ int s_cnt;
  if (threadIdx.x == 0) s_cnt = 0;
  __syncthreads();
  const ushort_t* u = (const ushort_t*)f;
  int c = 0;
  for (int j = 0; j < 4; ++j) {
    ushort_t v = u[(threadIdx.x * 4 + j) * 2];
    int e = (v >> 7) & 0xFF;
    if (e > 100 && e < 140) ++c;
  }
  atomicAdd(&s_cnt, c);
  __syncthreads();
  if (threadIdx.x == 0) ((uint_t*)ws)[0] = (s_cnt >= 160) ? 1u : 0u;
}

__global__ void prep_bias(const void* __restrict__ b0, const void* __restrict__ b1,
                          const void* __restrict__ b2, const void* __restrict__ b3,
                          const void* __restrict__ bsig, const void* __restrict__ brgb,
                          ushort_t* __restrict__ ws) {
  const int isbf = (int)((const uint_t*)ws)[0];
  int i = threadIdx.x;
  ws[OFF_B0 + i] = ldbf(b0, i, isbf);
  ws[OFF_B1 + i] = ldbf(b1, i, isbf);
  ws[OFF_B2 + i] = ldbf(b2, i, isbf);
  ws[OFF_B3 + i] = ldbf(b3, i, isbf);
  if (i == 0) ws[OFF_BSIG] = ldbf(bsig, 0, isbf);
  if (i < 3) ws[OFF_BRGB + i] = ldbf(brgb, i, isbf);
}

// ------------------------------------------------------------------
// prep: swizzle weights into MFMA B-fragment-native layout
// ------------------------------------------------------------------
__global__ void prep_weights(const void* __restrict__ W0,
                             const void* __restrict__ W1,
                             const void* __restrict__ W2,
                             const void* __restrict__ W3,
                             const void* __restrict__ Wsig,
                             const void* __restrict__ Wrgb,
                             ushort_t* __restrict__ ws) {
  const int isbf = (int)((const uint_t*)ws)[0];
  int t = blockIdx.x * 256 + threadIdx.x;   // 424 tiles * 64 lanes = 27136
  int lane = t & 63;
  int tile = t >> 6;
  const void* src = nullptr;
  ushort_t* dst;
  int kt, nt, Ksrc = 256;
  bool head = false;
  if (tile < 32) {            // L0: 47x256 padded to 64x256
    kt = tile >> 4; nt = tile & 15; src = W0; Ksrc = 47;
    dst = ws + OFF_W0 + (size_t)tile * 512;
  } else if (tile < 160) {
    int tl = tile - 32; kt = tl >> 4; nt = tl & 15; src = W1;
    dst = ws + OFF_W1 + (size_t)tl * 512;
  } else if (tile < 288) {
    int tl = tile - 160; kt = tl >> 4; nt = tl & 15; src = W2;
    dst = ws + OFF_W2 + (size_t)tl * 512;
  } else if (tile < 416) {
    int tl = tile - 288; kt = tl >> 4; nt = tl & 15; src = W3;
    dst = ws + OFF_W3 + (size_t)tl * 512;
  } else {                    // head: cols 0..2 = W_rgb, col 3 = W_sig
    int tl = tile - 416; kt = tl; nt = 0; head = true;
    dst = ws + OFF_WH + (size_t)tl * 512;
  }
  int n = nt * 16 + (lane & 15);
  int kb = kt * 32 + (lane >> 4) * 8;
  for (int i = 0; i < 8; ++i) {
    int k = kb + i;
    ushort_t v = 0;
    if (head) {
      if (n < 3) v = ldbf(Wrgb, (long)k * 3 + n, isbf);
      else if (n == 3) v = ldbf(Wsig, k, isbf);
    } else if (k < Ksrc) {
      v = ldbf(src, (long)k * 256 + n, isbf);
    }
    dst[lane * 8 + i] = v;
  }
}

// transpose planes from [rank][pos] to [pos][rank]
__global__ void prep_planes(const void* __restrict__ fxy,
                            const void* __restrict__ fxz,
                            const void* __restrict__ fyz,
                            ushort_t* __restrict__ ws) {
  const int isbf = (int)((const uint_t*)ws)[0];
  int t = blockIdx.x * 256 + threadIdx.x;   // 3*16384 = 49152
  int plane = t >> 14, pos = t & 16383;
  const void* src = (plane == 0) ? fxy : (plane == 1) ? fxz : fyz;
  ushort_t* d = ws + OFF_PL + (size_t)plane * 131072 + (size_t)pos * 8;
  for (int r = 0; r < 8; ++r) d[r] = ldbf(src, (long)r * 16384 + pos, isbf);
}

// ------------------------------------------------------------------
// main fused kernel: 1 block = 128 points, 8 waves in 2x4 tile grid.
// Register budget is the whole game: acc (64 AGPR) + a[4]/b[4] (32) +
// addressing must stay under the 128-reg wave budget of (512,4).
// kt-loop kept at unroll 1; b-loads use ONE base pointer + imm offsets
// (c*1024B) advanced 16KB/kt; a-swizzle recomputed from 4 persistent
// ints (2 VALU each). Round-4 evidence: 1.05 GB phantom WRITE_SIZE
// from ~2-3 regs spilled in the inner loop.
// ------------------------------------------------------------------
template <int KT>
__device__ __forceinline__ void mlp_layer(ushort_t* s_act,
                                          const ushort_t* __restrict__ wsW,
                                          const ushort_t* __restrict__ bias,
                                          int wrow, int wcol, int lane) {
  f32x4 acc[4][4] = {};
  const int m0 = lane & 15;
  const int q = lane >> 4;
  int abase[4], axor[4];
#pragma unroll
  for (int t = 0; t < 4; ++t) {
    int row = wrow * 64 + t * 16 + m0;
    abase[t] = row * 256;
    axor[t] = row & 31;
  }
  const ushort_t* bptr = wsW + (size_t)((wcol * 4) * 64 + lane) * 8;
#pragma unroll 1
  for (int kt = 0; kt < KT; ++kt) {
    bf16x8 b[4];
#pragma unroll
    for (int c = 0; c < 4; ++c) {
      union { uint4 u; bf16x8 v; } tmp;
      tmp.u = *(const uint4*)(bptr + c * 512);   // imm offsets 0/1/2/3 KB
      b[c] = tmp.v;
    }
    bf16x8 a[4];
    int kq = kt * 4 + q;
#pragma unroll
    for (int t = 0; t < 4; ++t) {
      union { uint4 u; bf16x8 v; } tmp;
      tmp.u = *(const uint4*)(s_act + abase[t] + ((kq ^ axor[t]) << 3));
      a[t] = tmp.v;
    }
#pragma unroll
    for (int t = 0; t < 4; ++t)
#pragma unroll
      for (int c = 0; c < 4; ++c)
        acc[t][c] = __builtin_amdgcn_mfma_f32_16x16x32_bf16(a[t], b[c], acc[t][c], 0, 0, 0);
    bptr += 16 * 512;   // next K-tile row of weight tiles
  }
  __syncthreads();   // all waves done reading act
#pragma unroll
  for (int c = 0; c < 4; ++c) {
    int col = wcol * 64 + c * 16 + m0;
    float bf = bf2f(bias[col]);
#pragma unroll
    for (int t = 0; t < 4; ++t) {
#pragma unroll
      for (int r = 0; r < 4; ++r) {
        float v = acc[t][c][r] + bf;
        v = fmaxf(v, 0.0f);
        int row = wrow * 64 + t * 16 + q * 4 + r;
        s_act[act_addr(row, col)] = f2bf(v);
      }
    }
  }
  __syncthreads();   // act ready for next layer
}

__global__ __launch_bounds__(512, 4)
void tensorf_main(const void* __restrict__ x,
                  const ushort_t* __restrict__ ws,
                  void* __restrict__ out) {
  __shared__ ushort_t s_act[128 * 256];   // 64 KB, XOR-swizzled
  const int isbf = (int)((const uint_t*)ws)[0];
  const int tid = threadIdx.x;
  const int lane = tid & 63;
  const int wid = tid >> 6;        // 0..7
  const int wrow = wid >> 2;       // 0..1
  const int wcol = wid & 3;        // 0..3
  const int blk = blockIdx.x;

  // ---- Phase A: features + positional encoding into s_act[:, 0:64] ----
  // 4 threads per point: s=0 gather+x, s=1..3 trig windows of 12 cols
  {
    int pl = tid >> 2;            // 0..127
    int s = tid & 3;
    long p = (long)blk * 128 + pl;
    float x0 = ldf(x, p * 3 + 0, isbf);
    float x1 = ldf(x, p * 3 + 1, isbf);
    float x2 = ldf(x, p * 3 + 2, isbf);
    if (s == 0) {
      // match np: idx = trunc((x+1.0)*0.5*127), clip to [0,127]
      int ix = (int)(((x0 + 1.0f) * 0.5f) * 127.0f);
      int iy = (int)(((x1 + 1.0f) * 0.5f) * 127.0f);
      int iz = (int)(((x2 + 1.0f) * 0.5f) * 127.0f);
      ix = ix < 0 ? 0 : (ix > 127 ? 127 : ix);
      iy = iy < 0 ? 0 : (iy > 127 ? 127 : iy);
      iz = iz < 0 ? 0 : (iz > 127 ? 127 : iz);
      union { uint4 u; ushort_t s[8]; } a, b, c;
      a.u = *(const uint4*)(ws + OFF_PL + (size_t)(iy * 128 + ix) * 8);
      b.u = *(const uint4*)(ws + OFF_PL + 131072 + (size_t)(iz * 128 + ix) * 8);
      c.u = *(const uint4*)(ws + OFF_PL + 262144 + (size_t)(iz * 128 + iy) * 8);
#pragma unroll
      for (int r = 0; r < 8; ++r) {
        float f = bf2f(a.s[r]) + bf2f(b.s[r]) + bf2f(c.s[r]);
        s_act[act_addr(pl, r)] = f2bf(f);
      }
      s_act[act_addr(pl, 8)]  = f2bf(x0);
      s_act[act_addr(pl, 9)]  = f2bf(x1);
      s_act[act_addr(pl, 10)] = f2bf(x2);
#pragma unroll
      for (int k = 47; k < 64; ++k) s_act[act_addr(pl, k)] = 0;
    } else {
      float fx[3] = { x0, x1, x2 };
      int k0 = 11 + (s - 1) * 12;
#pragma unroll
      for (int j = 0; j < 12; ++j) {
        int k = k0 + j;
        int jj = k - 11;
        int l = jj / 6, rem = jj % 6;
        float ang = fx[rem % 3] * (float)(1 << l);
        float v = (rem < 3) ? __sinf(ang) : __cosf(ang);
        s_act[act_addr(pl, k)] = f2bf(v);
      }
    }
  }
  __syncthreads();

  mlp_layer<2>(s_act, ws + OFF_W0, ws + OFF_B0, wrow, wcol, lane);
  mlp_layer<8>(s_act, ws + OFF_W1, ws + OFF_B1, wrow, wcol, lane);
  mlp_layer<8>(s_act, ws + OFF_W2, ws + OFF_B2, wrow, wcol, lane);
  mlp_layer<8>(s_act, ws + OFF_W3, ws + OFF_B3, wrow, wcol, lane);

  // ---- head: [128x256] @ [256x16]; each wave does 16 rows ----
  {
    f32x4 acc = {};
    const int m0 = lane & 15;
    const int q = lane >> 4;
    const ushort_t* wh = ws + OFF_WH;
#pragma unroll
    for (int kt = 0; kt < 8; ++kt) {
      union { uint4 u; bf16x8 v; } tb;
      tb.u = *(const uint4*)(wh + ((size_t)(kt * 64 + lane) * 8));
      int row = wid * 16 + m0;
      int addr = row * 256 + (((kt * 4 + q) ^ (row & 31)) << 3);
      union { uint4 u; bf16x8 v; } ta;
      ta.u = *(const uint4*)(s_act + addr);
      acc = __builtin_amdgcn_mfma_f32_16x16x32_bf16(ta.v, tb.v, acc, 0, 0, 0);
    }
    float br0 = bf2f(ws[OFF_BRGB + 0]), br1 = bf2f(ws[OFF_BRGB + 1]), br2 = bf2f(ws[OFF_BRGB + 2]);
    float bs = bf2f(ws[OFF_BSIG]);
    int col = lane & 15;
#pragma unroll
    for (int r = 0; r < 4; ++r) {
      int row = wid * 16 + q * 4 + r;
      long p = (long)blk * 128 + row;
      float v = acc[r];
      if (col == 3) {
        float z = v + bs;
        float sp = (z > 20.0f) ? z : __logf(1.0f + __expf(z));
        stf(out, (long)3 * NPTS + p, isbf, sp);
      } else if (col < 3) {
        float z = v + (col == 0 ? br0 : (col == 1 ? br1 : br2));
        float sg = 1.0f / (1.0f + __expf(-z));
        stf(out, p * 3 + col, isbf, sg);
      }
    }
  }
}

extern "C" void kernel_launch(void* const* d_in, const int* in_sizes, int n_in,
                              void* d_out, int out_size, void* d_ws, size_t ws_size,
                              hipStream_t stream) {
  const void* x    = d_in[0];
  const void* fxy  = d_in[1];
  const void* fxz  = d_in[2];
  const void* fyz  = d_in[3];
  const void* W0   = d_in[4];
  const void* b0   = d_in[5];
  const void* W1   = d_in[6];
  const void* b1   = d_in[7];
  const void* W2   = d_in[8];
  const void* b2   = d_in[9];
  const void* W3   = d_in[10];
  const void* b3   = d_in[11];
  const void* Wsig = d_in[12];
  const void* bsig = d_in[13];
  const void* Wrgb = d_in[14];
  const void* brgb = d_in[15];
  ushort_t* ws = (ushort_t*)d_ws;

  hipLaunchKernelGGL(sniff_dtype, dim3(1), dim3(64), 0, stream, fxy, ws);
  hipLaunchKernelGGL(prep_bias, dim3(1), dim3(256), 0, stream,
                     b0, b1, b2, b3, bsig, brgb, ws);
  hipLaunchKernelGGL(prep_weights, dim3(106), dim3(256), 0, stream,
                     W0, W1, W2, W3, Wsig, Wrgb, ws);
  hipLaunchKernelGGL(prep_planes, dim3(192), dim3(256), 0, stream,
                     fxy, fxz, fyz, ws);
  hipLaunchKernelGGL(tensorf_main, dim3(8192), dim3(512), 0, stream,
                     x, ws, d_out);
}

// Round 6
// 644.077 us; speedup vs baseline: 1.5027x; 1.5027x over previous
//
#include <hip/hip_runtime.h>

typedef unsigned short ushort_t;
typedef unsigned int uint_t;

typedef __bf16 bf16x8 __attribute__((ext_vector_type(8)));
typedef float f32x4 __attribute__((ext_vector_type(4)));

#define NPTS (1 << 20)

// ---- ws layout (ushort units) ----
#define OFF_FLAG 0        // uint flag at ws[0..1]: 1 = inputs are bf16, 0 = fp32
#define OFF_B0   16
#define OFF_B1   272
#define OFF_B2   528
#define OFF_B3   784
#define OFF_BSIG 1040
#define OFF_BRGB 1041
#define OFF_W0   1056     // K=64 (47 padded), N=256: 32 tiles * 512 (A-frag layout W^T)
#define OFF_W1   17440    // K=256,N=256: 128 tiles * 512
#define OFF_W2   82976
#define OFF_W3   148512
#define OFF_WH   214048   // K=256,N=16 (rgb0,rgb1,rgb2,sig,0...): 8 tiles * 512
#define OFF_PL   218144   // transposed planes [plane][pos(16384)][rank(8)]

__device__ __forceinline__ float bf2f(ushort_t u) {
  union { uint_t i; float f; } c; c.i = ((uint_t)u) << 16; return c.f;
}
__device__ __forceinline__ ushort_t f2bf(float f) {
  union { float f; uint_t i; } c; c.f = f;
  uint_t x = c.i;
  return (ushort_t)((x + 0x7fffu + ((x >> 16) & 1u)) >> 16);
}
// dtype-branched scalar loads
__device__ __forceinline__ float ldf(const void* p, long i, int isbf) {
  return isbf ? bf2f(((const ushort_t*)p)[i]) : ((const float*)p)[i];
}
__device__ __forceinline__ ushort_t ldbf(const void* p, long i, int isbf) {
  return isbf ? ((const ushort_t*)p)[i] : f2bf(((const float*)p)[i]);
}
__device__ __forceinline__ void stf(void* p, long i, int isbf, float v) {
  if (isbf) ((ushort_t*)p)[i] = f2bf(v);
  else      ((float*)p)[i] = v;
}

// XOR-swizzled LDS activation address (row-major 64 x 256 bf16, 16B-group swizzle)
// element (point row, col k) -> 2-way max bank aliasing for frag reads (free, m136)
__device__ __forceinline__ int act_addr(int row, int k) {
  return row * 256 + ((((k >> 3) ^ (row & 31)) << 3) | (k & 7));
}

// ------------------------------------------------------------------
// sniff: decide whether inputs are stored as bf16 or fp32.
// ------------------------------------------------------------------
__global__ void sniff_dtype(const void* __restrict__ f, ushort_t* __restrict__ ws) {
  __shared__ int s_cnt;
  if (threadIdx.x == 0) s_cnt = 0;
  __syncthreads();
  const ushort_t* u = (const ushort_t*)f;
  int c = 0;
  for (int j = 0; j < 4; ++j) {
    ushort_t v = u[(threadIdx.x * 4 + j) * 2];
    int e = (v >> 7) & 0xFF;
    if (e > 100 && e < 140) ++c;
  }
  atomicAdd(&s_cnt, c);
  __syncthreads();
  if (threadIdx.x == 0) ((uint_t*)ws)[0] = (s_cnt >= 160) ? 1u : 0u;
}

__global__ void prep_bias(const void* __restrict__ b0, const void* __restrict__ b1,
                          const void* __restrict__ b2, const void* __restrict__ b3,
                          const void* __restrict__ bsig, const void* __restrict__ brgb,
                          ushort_t* __restrict__ ws) {
  const int isbf = (int)((const uint_t*)ws)[0];
  int i = threadIdx.x;
  ws[OFF_B0 + i] = ldbf(b0, i, isbf);
  ws[OFF_B1 + i] = ldbf(b1, i, isbf);
  ws[OFF_B2 + i] = ldbf(b2, i, isbf);
  ws[OFF_B3 + i] = ldbf(b3, i, isbf);
  if (i == 0) ws[OFF_BSIG] = ldbf(bsig, 0, isbf);
  if (i < 3) ws[OFF_BRGB + i] = ldbf(brgb, i, isbf);
}

// ------------------------------------------------------------------
// prep: weights into MFMA A-fragment layout for W^T (lane m = out-col,
// k spread over quad*8+j). Same index mapping as before, reinterpreted.
// ------------------------------------------------------------------
__global__ void prep_weights(const void* __restrict__ W0,
                             const void* __restrict__ W1,
                             const void* __restrict__ W2,
                             const void* __restrict__ W3,
                             const void* __restrict__ Wsig,
                             const void* __restrict__ Wrgb,
                             ushort_t* __restrict__ ws) {
  const int isbf = (int)((const uint_t*)ws)[0];
  int t = blockIdx.x * 256 + threadIdx.x;   // 424 tiles * 64 lanes = 27136
  int lane = t & 63;
  int tile = t >> 6;
  const void* src = nullptr;
  ushort_t* dst;
  int kt, nt, Ksrc = 256;
  bool head = false;
  if (tile < 32) {            // L0: 47x256 padded to 64x256
    kt = tile >> 4; nt = tile & 15; src = W0; Ksrc = 47;
    dst = ws + OFF_W0 + (size_t)tile * 512;
  } else if (tile < 160) {
    int tl = tile - 32; kt = tl >> 4; nt = tl & 15; src = W1;
    dst = ws + OFF_W1 + (size_t)tl * 512;
  } else if (tile < 288) {
    int tl = tile - 160; kt = tl >> 4; nt = tl & 15; src = W2;
    dst = ws + OFF_W2 + (size_t)tl * 512;
  } else if (tile < 416) {
    int tl = tile - 288; kt = tl >> 4; nt = tl & 15; src = W3;
    dst = ws + OFF_W3 + (size_t)tl * 512;
  } else {                    // head: cols 0..2 = W_rgb, col 3 = W_sig
    int tl = tile - 416; kt = tl; nt = 0; head = true;
    dst = ws + OFF_WH + (size_t)tl * 512;
  }
  int n = nt * 16 + (lane & 15);        // out-col (A-frag m)
  int kb = kt * 32 + (lane >> 4) * 8;   // in-col (A-frag k)
  for (int i = 0; i < 8; ++i) {
    int k = kb + i;
    ushort_t v = 0;
    if (head) {
      if (n < 3) v = ldbf(Wrgb, (long)k * 3 + n, isbf);
      else if (n == 3) v = ldbf(Wsig, k, isbf);
    } else if (k < Ksrc) {
      v = ldbf(src, (long)k * 256 + n, isbf);
    }
    dst[lane * 8 + i] = v;
  }
}

// transpose planes from [rank][pos] to [pos][rank]
__global__ void prep_planes(const void* __restrict__ fxy,
                            const void* __restrict__ fxz,
                            const void* __restrict__ fyz,
                            ushort_t* __restrict__ ws) {
  const int isbf = (int)((const uint_t*)ws)[0];
  int t = blockIdx.x * 256 + threadIdx.x;   // 3*16384 = 49152
  int plane = t >> 14, pos = t & 16383;
  const void* src = (plane == 0) ? fxy : (plane == 1) ? fxz : fyz;
  ushort_t* d = ws + OFF_PL + (size_t)plane * 131072 + (size_t)pos * 8;
  for (int r = 0; r < 8; ++r) d[r] = ldbf(src, (long)r * 16384 + pos, isbf);
}

// ------------------------------------------------------------------
// main fused kernel, orientation D = W^T · Act^T:
//   A operand = W^T (from ws, prepped frags), B operand = Act^T (LDS,
//   b128 contiguous reads), D: lane = point, regs = 4 consecutive
//   out-cols -> pack -> ds_write_b64 contiguous. This kills the scalar
//   epilogue writes of the old orientation.
// Block = 512 thr / 8 waves, 64 points x 256 cols; wave grid 4(m) x 2(n),
// wave tile 64 out-cols x 32 points -> acc[4][2] = 32 VGPRs (rounds 3-5
// showed acc=64 + operands can't live under the 128-reg cap without
// spilling ~0.5-1 GB of phantom scratch traffic).
// ------------------------------------------------------------------
template <int KT>
__device__ __forceinline__ void mlp_layer(ushort_t* s_act,
                                          const ushort_t* __restrict__ wsW,
                                          const ushort_t* __restrict__ bias,
                                          int mg, int ng, int lane) {
  f32x4 acc[4][2] = {};
  const int m0 = lane & 15;
  const int q = lane >> 4;
  int pbase[2], pxor[2];
#pragma unroll
  for (int d = 0; d < 2; ++d) {
    int p = (ng * 2 + d) * 16 + m0;
    pbase[d] = p * 256;
    pxor[d] = p & 31;
  }
#pragma unroll 1
  for (int kt = 0; kt < KT; ++kt) {
    const ushort_t* ap = wsW + (size_t)(kt * 16 + mg * 4) * 512 + lane * 8;
    bf16x8 a[4];
#pragma unroll
    for (int c = 0; c < 4; ++c) {
      union { uint4 u; bf16x8 v; } tmp;
      tmp.u = *(const uint4*)(ap + c * 512);   // imm offsets 0/1/2/3 KB
      a[c] = tmp.v;
    }
    bf16x8 b[2];
    int kq = kt * 4 + q;
#pragma unroll
    for (int d = 0; d < 2; ++d) {
      union { uint4 u; bf16x8 v; } tmp;
      tmp.u = *(const uint4*)(s_act + pbase[d] + ((kq ^ pxor[d]) << 3));
      b[d] = tmp.v;
    }
#pragma unroll
    for (int c = 0; c < 4; ++c)
#pragma unroll
      for (int d = 0; d < 2; ++d)
        acc[c][d] = __builtin_amdgcn_mfma_f32_16x16x32_bf16(a[c], b[d], acc[c][d], 0, 0, 0);
  }
  __syncthreads();   // all waves done reading act
#pragma unroll
  for (int c = 0; c < 4; ++c) {
    int col0 = mg * 64 + c * 16 + q * 4;      // 4 consecutive out-cols
    ushort4 bb = *(const ushort4*)(bias + col0);
    float bf0 = bf2f(bb.x), bf1 = bf2f(bb.y), bf2v = bf2f(bb.z), bf3 = bf2f(bb.w);
    int g = col0 >> 3;                        // 16B-group index
    int goff = (q & 1) * 4;                   // ushort offset within group
#pragma unroll
    for (int d = 0; d < 2; ++d) {
      float v0 = fmaxf(acc[c][d][0] + bf0, 0.0f);
      float v1 = fmaxf(acc[c][d][1] + bf1, 0.0f);
      float v2 = fmaxf(acc[c][d][2] + bf2v, 0.0f);
      float v3 = fmaxf(acc[c][d][3] + bf3, 0.0f);
      uint_t lo = (uint_t)f2bf(v0) | ((uint_t)f2bf(v1) << 16);
      uint_t hi = (uint_t)f2bf(v2) | ((uint_t)f2bf(v3) << 16);
      int idx = pbase[d] + ((g ^ pxor[d]) << 3) + goff;
      uint2 pk; pk.x = lo; pk.y = hi;
      *(uint2*)(s_act + idx) = pk;            // ds_write_b64, contiguous cols
    }
  }
  __syncthreads();   // act ready for next layer
}

__global__ __launch_bounds__(512, 4)
void tensorf_main(const void* __restrict__ x,
                  const ushort_t* __restrict__ ws,
                  void* __restrict__ out) {
  __shared__ ushort_t s_act[64 * 256];   // 32 KB, XOR-swizzled [point][col]
  const int isbf = (int)((const uint_t*)ws)[0];
  const int tid = threadIdx.x;
  const int lane = tid & 63;
  const int wid = tid >> 6;        // 0..7
  const int mg = wid >> 1;         // 0..3 (out-col group)
  const int ng = wid & 1;          // 0..1 (point group)
  const int blk = blockIdx.x;

  // ---- Phase A: features + positional encoding into s_act[:, 0:64] ----
  // 8 threads per point: s=0 gather+x; s=1..6 trig level l=s-1; s=7 zero pad
  {
    int pl = tid >> 3;            // 0..63
    int s = tid & 7;
    long p = (long)blk * 64 + pl;
    float x0 = ldf(x, p * 3 + 0, isbf);
    float x1 = ldf(x, p * 3 + 1, isbf);
    float x2 = ldf(x, p * 3 + 2, isbf);
    if (s == 0) {
      // match np: idx = trunc((x+1.0)*0.5*127), clip to [0,127]
      int ix = (int)(((x0 + 1.0f) * 0.5f) * 127.0f);
      int iy = (int)(((x1 + 1.0f) * 0.5f) * 127.0f);
      int iz = (int)(((x2 + 1.0f) * 0.5f) * 127.0f);
      ix = ix < 0 ? 0 : (ix > 127 ? 127 : ix);
      iy = iy < 0 ? 0 : (iy > 127 ? 127 : iy);
      iz = iz < 0 ? 0 : (iz > 127 ? 127 : iz);
      union { uint4 u; ushort_t s[8]; } a, b, c;
      a.u = *(const uint4*)(ws + OFF_PL + (size_t)(iy * 128 + ix) * 8);
      b.u = *(const uint4*)(ws + OFF_PL + 131072 + (size_t)(iz * 128 + ix) * 8);
      c.u = *(const uint4*)(ws + OFF_PL + 262144 + (size_t)(iz * 128 + iy) * 8);
#pragma unroll
      for (int r = 0; r < 8; ++r) {
        float f = bf2f(a.s[r]) + bf2f(b.s[r]) + bf2f(c.s[r]);
        s_act[act_addr(pl, r)] = f2bf(f);
      }
      s_act[act_addr(pl, 8)]  = f2bf(x0);
      s_act[act_addr(pl, 9)]  = f2bf(x1);
      s_act[act_addr(pl, 10)] = f2bf(x2);
    } else if (s == 7) {
#pragma unroll
      for (int k = 47; k < 64; ++k) s_act[act_addr(pl, k)] = 0;
    } else {
      int l = s - 1;
      float fr = (float)(1 << l);
      float fx[3] = { x0, x1, x2 };
      int k0 = 11 + l * 6;
#pragma unroll
      for (int dd = 0; dd < 3; ++dd) {
        float ang = fx[dd] * fr;
        s_act[act_addr(pl, k0 + dd)]     = f2bf(__sinf(ang));
        s_act[act_addr(pl, k0 + 3 + dd)] = f2bf(__cosf(ang));
      }
    }
  }
  __syncthreads();

  mlp_layer<2>(s_act, ws + OFF_W0, ws + OFF_B0, mg, ng, lane);
  mlp_layer<8>(s_act, ws + OFF_W1, ws + OFF_B1, mg, ng, lane);
  mlp_layer<8>(s_act, ws + OFF_W2, ws + OFF_B2, mg, ng, lane);
  mlp_layer<8>(s_act, ws + OFF_W3, ws + OFF_B3, mg, ng, lane);

  // ---- head: D = Wh^T(4x256) · Act^T; waves 0..3 take 16 points each ----
  if (wid < 4) {
    f32x4 acc = {};
    const int m0 = lane & 15;
    const int q = lane >> 4;
    int p = wid * 16 + m0;
    int pb = p * 256, px = p & 31;
    const ushort_t* wh = ws + OFF_WH;
#pragma unroll
    for (int kt = 0; kt < 8; ++kt) {
      union { uint4 u; bf16x8 v; } ta, tb;
      ta.u = *(const uint4*)(wh + (size_t)kt * 512 + lane * 8);
      tb.u = *(const uint4*)(s_act + pb + (((kt * 4 + q) ^ px) << 3));
      acc = __builtin_amdgcn_mfma_f32_16x16x32_bf16(ta.v, tb.v, acc, 0, 0, 0);
    }
    if (q == 0) {   // regs r = out-cols 0..3 = rgb0, rgb1, rgb2, sigma
      long pp = (long)blk * 64 + p;
      float br0 = bf2f(ws[OFF_BRGB + 0]), br1 = bf2f(ws[OFF_BRGB + 1]), br2 = bf2f(ws[OFF_BRGB + 2]);
      float bs = bf2f(ws[OFF_BSIG]);
      float z0 = acc[0] + br0, z1 = acc[1] + br1, z2 = acc[2] + br2;
      stf(out, pp * 3 + 0, isbf, 1.0f / (1.0f + __expf(-z0)));
      stf(out, pp * 3 + 1, isbf, 1.0f / (1.0f + __expf(-z1)));
      stf(out, pp * 3 + 2, isbf, 1.0f / (1.0f + __expf(-z2)));
      float zs = acc[3] + bs;
      float sp = (zs > 20.0f) ? zs : __logf(1.0f + __expf(zs));
      stf(out, (long)3 * NPTS + pp, isbf, sp);
    }
  }
}

extern "C" void kernel_launch(void* const* d_in, const int* in_sizes, int n_in,
                              void* d_out, int out_size, void* d_ws, size_t ws_size,
                              hipStream_t stream) {
  const void* x    = d_in[0];
  const void* fxy  = d_in[1];
  const void* fxz  = d_in[2];
  const void* fyz  = d_in[3];
  const void* W0   = d_in[4];
  const void* b0   = d_in[5];
  const void* W1   = d_in[6];
  const void* b1   = d_in[7];
  const void* W2   = d_in[8];
  const void* b2   = d_in[9];
  const void* W3   = d_in[10];
  const void* b3   = d_in[11];
  const void* Wsig = d_in[12];
  const void* bsig = d_in[13];
  const void* Wrgb = d_in[14];
  const void* brgb = d_in[15];
  ushort_t* ws = (ushort_t*)d_ws;

  hipLaunchKernelGGL(sniff_dtype, dim3(1), dim3(64), 0, stream, fxy, ws);
  hipLaunchKernelGGL(prep_bias, dim3(1), dim3(256), 0, stream,
                     b0, b1, b2, b3, bsig, brgb, ws);
  hipLaunchKernelGGL(prep_weights, dim3(106), dim3(256), 0, stream,
                     W0, W1, W2, W3, Wsig, Wrgb, ws);
  hipLaunchKernelGGL(prep_planes, dim3(192), dim3(256), 0, stream,
                     fxy, fxz, fyz, ws);
  hipLaunchKernelGGL(tensorf_main, dim3(16384), dim3(512), 0, stream,
                     x, ws, d_out);
}

// Round 7
// 628.913 us; speedup vs baseline: 1.5389x; 1.0241x over previous
//
#include <hip/hip_runtime.h>
#include <hip/hip_bf16.h>

typedef unsigned short ushort_t;
typedef unsigned int uint_t;

typedef __bf16 bf16x8 __attribute__((ext_vector_type(8)));
typedef float f32x4 __attribute__((ext_vector_type(4)));

#define NPTS (1 << 20)
#define SROW 264   // LDS row stride in ushorts: 264 dwords%32 = 4 -> 2-way max aliasing (free)

// ---- ws layout (ushort units) ----
#define OFF_FLAG 0        // uint flag at ws[0..1]: 1 = inputs are bf16, 0 = fp32
#define OFF_B0   16
#define OFF_B1   272
#define OFF_B2   528
#define OFF_B3   784
#define OFF_BSIG 1040
#define OFF_BRGB 1041
#define OFF_W0   1056     // K=64 (47 padded), N=256: 32 tiles * 512 (A-frag layout W^T)
#define OFF_W1   17440    // K=256,N=256: 128 tiles * 512
#define OFF_W2   82976
#define OFF_W3   148512
#define OFF_WH   214048   // K=256,N=16 (rgb0,rgb1,rgb2,sig,0...): 8 tiles * 512
#define OFF_PL   218144   // transposed planes [plane][pos(16384)][rank(8)]

__device__ __forceinline__ float bf2f(ushort_t u) {
  union { uint_t i; float f; } c; c.i = ((uint_t)u) << 16; return c.f;
}
__device__ __forceinline__ ushort_t f2bf(float f) {
  union { float f; uint_t i; } c; c.f = f;
  uint_t x = c.i;
  return (ushort_t)((x + 0x7fffu + ((x >> 16) & 1u)) >> 16);
}
// packed f32x2 -> bf16x2 (v_cvt_pk_bf16_f32 on gfx950)
__device__ __forceinline__ uint_t pk2bf(float a, float b) {
  __hip_bfloat162 h = __float22bfloat162_rn(float2{a, b});
  union { __hip_bfloat162 h; uint_t u; } c; c.h = h; return c.u;
}
// dtype-branched scalar loads
__device__ __forceinline__ float ldf(const void* p, long i, int isbf) {
  return isbf ? bf2f(((const ushort_t*)p)[i]) : ((const float*)p)[i];
}
__device__ __forceinline__ ushort_t ldbf(const void* p, long i, int isbf) {
  return isbf ? ((const ushort_t*)p)[i] : f2bf(((const float*)p)[i]);
}
__device__ __forceinline__ void stf(void* p, long i, int isbf, float v) {
  if (isbf) ((ushort_t*)p)[i] = f2bf(v);
  else      ((float*)p)[i] = v;
}

// plain padded-stride LDS address (row = point, k = feature col)
__device__ __forceinline__ int act_addr(int row, int k) {
  return row * SROW + k;
}

// ------------------------------------------------------------------
// sniff: decide whether inputs are stored as bf16 or fp32.
// ------------------------------------------------------------------
__global__ void sniff_dtype(const void* __restrict__ f, ushort_t* __restrict__ ws) {
  __shared__ int s_cnt;
  if (threadIdx.x == 0) s_cnt = 0;
  __syncthreads();
  const ushort_t* u = (const ushort_t*)f;
  int c = 0;
  for (int j = 0; j < 4; ++j) {
    ushort_t v = u[(threadIdx.x * 4 + j) * 2];
    int e = (v >> 7) & 0xFF;
    if (e > 100 && e < 140) ++c;
  }
  atomicAdd(&s_cnt, c);
  __syncthreads();
  if (threadIdx.x == 0) ((uint_t*)ws)[0] = (s_cnt >= 160) ? 1u : 0u;
}

__global__ void prep_bias(const void* __restrict__ b0, const void* __restrict__ b1,
                          const void* __restrict__ b2, const void* __restrict__ b3,
                          const void* __restrict__ bsig, const void* __restrict__ brgb,
                          ushort_t* __restrict__ ws) {
  const int isbf = (int)((const uint_t*)ws)[0];
  int i = threadIdx.x;
  ws[OFF_B0 + i] = ldbf(b0, i, isbf);
  ws[OFF_B1 + i] = ldbf(b1, i, isbf);
  ws[OFF_B2 + i] = ldbf(b2, i, isbf);
  ws[OFF_B3 + i] = ldbf(b3, i, isbf);
  if (i == 0) ws[OFF_BSIG] = ldbf(bsig, 0, isbf);
  if (i < 3) ws[OFF_BRGB + i] = ldbf(brgb, i, isbf);
}

// ------------------------------------------------------------------
// prep: weights into MFMA A-fragment layout for W^T (lane m = out-col,
// k = (lane>>4)*8 + i within a 32(k) x 16(n) tile).
// ------------------------------------------------------------------
__global__ void prep_weights(const void* __restrict__ W0,
                             const void* __restrict__ W1,
                             const void* __restrict__ W2,
                             const void* __restrict__ W3,
                             const void* __restrict__ Wsig,
                             const void* __restrict__ Wrgb,
                             ushort_t* __restrict__ ws) {
  const int isbf = (int)((const uint_t*)ws)[0];
  int t = blockIdx.x * 256 + threadIdx.x;   // 424 tiles * 64 lanes = 27136
  int lane = t & 63;
  int tile = t >> 6;
  const void* src = nullptr;
  ushort_t* dst;
  int kt, nt, Ksrc = 256;
  bool head = false;
  if (tile < 32) {            // L0: 47x256 padded to 64x256
    kt = tile >> 4; nt = tile & 15; src = W0; Ksrc = 47;
    dst = ws + OFF_W0 + (size_t)tile * 512;
  } else if (tile < 160) {
    int tl = tile - 32; kt = tl >> 4; nt = tl & 15; src = W1;
    dst = ws + OFF_W1 + (size_t)tl * 512;
  } else if (tile < 288) {
    int tl = tile - 160; kt = tl >> 4; nt = tl & 15; src = W2;
    dst = ws + OFF_W2 + (size_t)tl * 512;
  } else if (tile < 416) {
    int tl = tile - 288; kt = tl >> 4; nt = tl & 15; src = W3;
    dst = ws + OFF_W3 + (size_t)tl * 512;
  } else {                    // head: cols 0..2 = W_rgb, col 3 = W_sig
    int tl = tile - 416; kt = tl; nt = 0; head = true;
    dst = ws + OFF_WH + (size_t)tl * 512;
  }
  int n = nt * 16 + (lane & 15);        // out-col (A-frag m)
  int kb = kt * 32 + (lane >> 4) * 8;   // in-col (A-frag k)
  for (int i = 0; i < 8; ++i) {
    int k = kb + i;
    ushort_t v = 0;
    if (head) {
      if (n < 3) v = ldbf(Wrgb, (long)k * 3 + n, isbf);
      else if (n == 3) v = ldbf(Wsig, k, isbf);
    } else if (k < Ksrc) {
      v = ldbf(src, (long)k * 256 + n, isbf);
    }
    dst[lane * 8 + i] = v;
  }
}

// transpose planes from [rank][pos] to [pos][rank]
__global__ void prep_planes(const void* __restrict__ fxy,
                            const void* __restrict__ fxz,
                            const void* __restrict__ fyz,
                            ushort_t* __restrict__ ws) {
  const int isbf = (int)((const uint_t*)ws)[0];
  int t = blockIdx.x * 256 + threadIdx.x;   // 3*16384 = 49152
  int plane = t >> 14, pos = t & 16383;
  const void* src = (plane == 0) ? fxy : (plane == 1) ? fxz : fyz;
  ushort_t* d = ws + OFF_PL + (size_t)plane * 131072 + (size_t)pos * 8;
  for (int r = 0; r < 8; ++r) d[r] = ldbf(src, (long)r * 16384 + pos, isbf);
}

// ------------------------------------------------------------------
// main fused kernel, orientation D = W^T · Act^T.
// Block = 512 thr / 8 waves, 64 points x 256 cols; wave grid 4(m)x2(n);
// wave tile 64 out-cols x 32 points -> acc[4][2] = 32 VGPRs.
// Round-6 evidence: VALUBusy 62% vs MfmaUtil 33% — address VALU was the
// bottleneck. All K-loop LDS addresses are now base + compile-time
// immediates (padded stride SROW=264 instead of XOR swizzle); weight
// pointers advance on the scalar pipe; epilogue uses packed bf16 cvt.
// ------------------------------------------------------------------
template <int KT>
__device__ __forceinline__ void mlp_layer(ushort_t* s_act,
                                          const ushort_t* __restrict__ wsW,
                                          const ushort_t* __restrict__ bias,
                                          int mg, int ng, int lane) {
  f32x4 acc[4][2] = {};
  const int m0 = lane & 15;
  const int q = lane >> 4;
  // B-frag bases: act[point][k], k = (kt*4+q)*8 + j  ->  base + kt*64B imm
  const ushort_t* bbase0 = s_act + (ng * 32 + m0) * SROW + q * 8;
  const ushort_t* bbase1 = bbase0 + 16 * SROW;
  // A-frag base: uniform part folds to SGPR adds per kt
  const ushort_t* abase = wsW + (size_t)(mg * 4) * 512 + lane * 8;
#pragma unroll 2
  for (int kt = 0; kt < KT; ++kt) {
    bf16x8 a[4], b[2];
#pragma unroll
    for (int c = 0; c < 4; ++c) {
      union { uint4 u; bf16x8 v; } t;
      t.u = *(const uint4*)(abase + (size_t)kt * 8192 + c * 512);
      a[c] = t.v;
    }
    {
      union { uint4 u; bf16x8 v; } t0, t1;
      t0.u = *(const uint4*)(bbase0 + kt * 32);   // imm offset kt*64 B
      t1.u = *(const uint4*)(bbase1 + kt * 32);
      b[0] = t0.v; b[1] = t1.v;
    }
#pragma unroll
    for (int c = 0; c < 4; ++c)
#pragma unroll
      for (int d = 0; d < 2; ++d)
        acc[c][d] = __builtin_amdgcn_mfma_f32_16x16x32_bf16(a[c], b[d], acc[c][d], 0, 0, 0);
  }
  __syncthreads();   // all waves done reading act
  // D: lane m0 = point (16-group), regs = out-cols q*4+r; write base + c*32B imm
  ushort_t* wb0 = s_act + (ng * 32 + m0) * SROW + mg * 64 + q * 4;
  ushort_t* wb1 = wb0 + 16 * SROW;
#pragma unroll
  for (int c = 0; c < 4; ++c) {
    int col0 = mg * 64 + c * 16 + q * 4;      // 4 consecutive out-cols
    ushort4 bb = *(const ushort4*)(bias + col0);
    float bf0 = bf2f(bb.x), bf1 = bf2f(bb.y), bf2v = bf2f(bb.z), bf3 = bf2f(bb.w);
#pragma unroll
    for (int d = 0; d < 2; ++d) {
      const f32x4& A = acc[c][d];
      float v0 = fmaxf(A[0] + bf0, 0.0f);
      float v1 = fmaxf(A[1] + bf1, 0.0f);
      float v2 = fmaxf(A[2] + bf2v, 0.0f);
      float v3 = fmaxf(A[3] + bf3, 0.0f);
      uint2 pk; pk.x = pk2bf(v0, v1); pk.y = pk2bf(v2, v3);
      *(uint2*)((d ? wb1 : wb0) + c * 16) = pk;   // ds_write_b64, imm offset
    }
  }
  __syncthreads();   // act ready for next layer
}

__global__ __launch_bounds__(512, 4)
void tensorf_main(const void* __restrict__ x,
                  const ushort_t* __restrict__ ws,
                  void* __restrict__ out) {
  __shared__ ushort_t s_act[64 * SROW];   // 33 KB, padded stride
  const int isbf = (int)((const uint_t*)ws)[0];
  const int tid = threadIdx.x;
  const int lane = tid & 63;
  const int wid = tid >> 6;        // 0..7
  const int mg = wid >> 1;         // 0..3 (out-col group)
  const int ng = wid & 1;          // 0..1 (point group)
  const int blk = blockIdx.x;

  // ---- Phase A: features + positional encoding into s_act[:, 0:64] ----
  // 8 threads per point: s=0 gather+x; s=1..6 trig level l=s-1; s=7 zero pad
  {
    int pl = tid >> 3;            // 0..63
    int s = tid & 7;
    long p = (long)blk * 64 + pl;
    float x0 = ldf(x, p * 3 + 0, isbf);
    float x1 = ldf(x, p * 3 + 1, isbf);
    float x2 = ldf(x, p * 3 + 2, isbf);
    if (s == 0) {
      // match np: idx = trunc((x+1.0)*0.5*127), clip to [0,127]
      int ix = (int)(((x0 + 1.0f) * 0.5f) * 127.0f);
      int iy = (int)(((x1 + 1.0f) * 0.5f) * 127.0f);
      int iz = (int)(((x2 + 1.0f) * 0.5f) * 127.0f);
      ix = ix < 0 ? 0 : (ix > 127 ? 127 : ix);
      iy = iy < 0 ? 0 : (iy > 127 ? 127 : iy);
      iz = iz < 0 ? 0 : (iz > 127 ? 127 : iz);
      union { uint4 u; ushort_t s[8]; } a, b, c;
      a.u = *(const uint4*)(ws + OFF_PL + (size_t)(iy * 128 + ix) * 8);
      b.u = *(const uint4*)(ws + OFF_PL + 131072 + (size_t)(iz * 128 + ix) * 8);
      c.u = *(const uint4*)(ws + OFF_PL + 262144 + (size_t)(iz * 128 + iy) * 8);
      ushort_t* row = s_act + pl * SROW;
#pragma unroll
      for (int r = 0; r < 8; r += 2) {
        float f0 = bf2f(a.s[r]) + bf2f(b.s[r]) + bf2f(c.s[r]);
        float f1 = bf2f(a.s[r + 1]) + bf2f(b.s[r + 1]) + bf2f(c.s[r + 1]);
        *(uint_t*)(row + r) = pk2bf(f0, f1);
      }
      *(uint_t*)(row + 8) = pk2bf(x0, x1);
      row[10] = f2bf(x2);
    } else if (s == 7) {
      ushort_t* row = s_act + pl * SROW;
      row[47] = 0;
#pragma unroll
      for (int k = 48; k < 64; k += 4) *(uint2*)(row + k) = uint2{0u, 0u};
    } else {
      int l = s - 1;
      float fr = (float)(1 << l);
      float fx[3] = { x0, x1, x2 };
      ushort_t* row = s_act + pl * SROW + 11 + l * 6;
#pragma unroll
      for (int dd = 0; dd < 3; ++dd) {
        float ang = fx[dd] * fr;
        row[dd]     = f2bf(__sinf(ang));
        row[3 + dd] = f2bf(__cosf(ang));
      }
    }
  }
  __syncthreads();

  mlp_layer<2>(s_act, ws + OFF_W0, ws + OFF_B0, mg, ng, lane);
  mlp_layer<8>(s_act, ws + OFF_W1, ws + OFF_B1, mg, ng, lane);
  mlp_layer<8>(s_act, ws + OFF_W2, ws + OFF_B2, mg, ng, lane);
  mlp_layer<8>(s_act, ws + OFF_W3, ws + OFF_B3, mg, ng, lane);

  // ---- head: D = Wh^T(4x256) · Act^T; waves 0..3 take 16 points each ----
  if (wid < 4) {
    f32x4 acc = {};
    const int m0 = lane & 15;
    const int q = lane >> 4;
    int p = wid * 16 + m0;
    const ushort_t* hb = s_act + p * SROW + q * 8;
    const ushort_t* wh = ws + OFF_WH + lane * 8;
#pragma unroll
    for (int kt = 0; kt < 8; ++kt) {
      union { uint4 u; bf16x8 v; } ta, tb;
      ta.u = *(const uint4*)(wh + (size_t)kt * 512);
      tb.u = *(const uint4*)(hb + kt * 32);
      acc = __builtin_amdgcn_mfma_f32_16x16x32_bf16(ta.v, tb.v, acc, 0, 0, 0);
    }
    if (q == 0) {   // regs r = out-cols 0..3 = rgb0, rgb1, rgb2, sigma
      long pp = (long)blk * 64 + p;
      float br0 = bf2f(ws[OFF_BRGB + 0]), br1 = bf2f(ws[OFF_BRGB + 1]), br2 = bf2f(ws[OFF_BRGB + 2]);
      float bs = bf2f(ws[OFF_BSIG]);
      float z0 = acc[0] + br0, z1 = acc[1] + br1, z2 = acc[2] + br2;
      stf(out, pp * 3 + 0, isbf, 1.0f / (1.0f + __expf(-z0)));
      stf(out, pp * 3 + 1, isbf, 1.0f / (1.0f + __expf(-z1)));
      stf(out, pp * 3 + 2, isbf, 1.0f / (1.0f + __expf(-z2)));
      float zs = acc[3] + bs;
      float sp = (zs > 20.0f) ? zs : __logf(1.0f + __expf(zs));
      stf(out, (long)3 * NPTS + pp, isbf, sp);
    }
  }
}

extern "C" void kernel_launch(void* const* d_in, const int* in_sizes, int n_in,
                              void* d_out, int out_size, void* d_ws, size_t ws_size,
                              hipStream_t stream) {
  const void* x    = d_in[0];
  const void* fxy  = d_in[1];
  const void* fxz  = d_in[2];
  const void* fyz  = d_in[3];
  const void* W0   = d_in[4];
  const void* b0   = d_in[5];
  const void* W1   = d_in[6];
  const void* b1   = d_in[7];
  const void* W2   = d_in[8];
  const void* b2   = d_in[9];
  const void* W3   = d_in[10];
  const void* b3   = d_in[11];
  const void* Wsig = d_in[12];
  const void* bsig = d_in[13];
  const void* Wrgb = d_in[14];
  const void* brgb = d_in[15];
  ushort_t* ws = (ushort_t*)d_ws;

  hipLaunchKernelGGL(sniff_dtype, dim3(1), dim3(64), 0, stream, fxy, ws);
  hipLaunchKernelGGL(prep_bias, dim3(1), dim3(256), 0, stream,
                     b0, b1, b2, b3, bsig, brgb, ws);
  hipLaunchKernelGGL(prep_weights, dim3(106), dim3(256), 0, stream,
                     W0, W1, W2, W3, Wsig, Wrgb, ws);
  hipLaunchKernelGGL(prep_planes, dim3(192), dim3(256), 0, stream,
                     fxy, fxz, fyz, ws);
  hipLaunchKernelGGL(tensorf_main, dim3(16384), dim3(512), 0, stream,
                     x, ws, d_out);
}

// Round 8
// 608.262 us; speedup vs baseline: 1.5912x; 1.0340x over previous
//
#include <hip/hip_runtime.h>
#include <hip/hip_bf16.h>

typedef unsigned short ushort_t;
typedef unsigned int uint_t;

typedef __bf16 bf16x8 __attribute__((ext_vector_type(8)));
typedef float f32x4 __attribute__((ext_vector_type(4)));
typedef float f32x16 __attribute__((ext_vector_type(16)));

#define NPTS (1 << 20)

// ---- ws layout (ushort units) ----
// Weights stored as 32x32x16 MFMA A-fragments of W^T: tile = 32 out-cols (m)
// x 16 k; lane l: m = l&31, k = (l>>5)*8 + j. Tile order [kt][mt(8)].
#define OFF_FLAG 0        // uint flag: 1 = inputs bf16, 0 = fp32
#define OFF_B0   16
#define OFF_B1   272
#define OFF_B2   528
#define OFF_B3   784
#define OFF_BSIG 1040
#define OFF_BRGB 1041
#define OFF_W0   1056     // K=64 (47 padded): 4 kt x 8 mt = 32 tiles * 512
#define OFF_W1   17440    // K=256: 16 kt x 8 mt = 128 tiles * 512
#define OFF_W2   82976
#define OFF_W3   148512
#define OFF_WH   214048   // head: 16 kt x 1 mt (cols rgb0,rgb1,rgb2,sig,0..)
#define OFF_PL   222240   // transposed planes [plane][pos(16384)][rank(8)]

__device__ __forceinline__ float bf2f(ushort_t u) {
  union { uint_t i; float f; } c; c.i = ((uint_t)u) << 16; return c.f;
}
__device__ __forceinline__ ushort_t f2bf(float f) {
  union { float f; uint_t i; } c; c.f = f;
  uint_t x = c.i;
  return (ushort_t)((x + 0x7fffu + ((x >> 16) & 1u)) >> 16);
}
__device__ __forceinline__ uint_t pk2bf(float a, float b) {
  __hip_bfloat162 h = __float22bfloat162_rn(float2{a, b});
  union { __hip_bfloat162 h; uint_t u; } c; c.h = h; return c.u;
}
__device__ __forceinline__ float ldf(const void* p, long i, int isbf) {
  return isbf ? bf2f(((const ushort_t*)p)[i]) : ((const float*)p)[i];
}
__device__ __forceinline__ ushort_t ldbf(const void* p, long i, int isbf) {
  return isbf ? ((const ushort_t*)p)[i] : f2bf(((const float*)p)[i]);
}
__device__ __forceinline__ void stf(void* p, long i, int isbf, float v) {
  if (isbf) ((ushort_t*)p)[i] = f2bf(v);
  else      ((float*)p)[i] = v;
}

// Activation LDS layout = 32x32x16 B-fragment native:
// element (point p, col k) -> frag(ntile=p>>5, kt=k>>4), lane = ((k>>3)&1)*32
// + (p&31), j = k&7.  frag stride 512 ushorts, ntile stride 8192.
__device__ __forceinline__ int fragaddr(int p, int k) {
  return ((p >> 5) << 13) + ((k >> 4) << 9) + (((k >> 3) & 1) << 8)
       + ((p & 31) << 3) + (k & 7);
}

// ------------------------------------------------------------------
__global__ void sniff_dtype(const void* __restrict__ f, ushort_t* __restrict__ ws) {
  __shared__ int s_cnt;
  if (threadIdx.x == 0) s_cnt = 0;
  __syncthreads();
  const ushort_t* u = (const ushort_t*)f;
  int c = 0;
  for (int j = 0; j < 4; ++j) {
    ushort_t v = u[(threadIdx.x * 4 + j) * 2];
    int e = (v >> 7) & 0xFF;
    if (e > 100 && e < 140) ++c;
  }
  atomicAdd(&s_cnt, c);
  __syncthreads();
  if (threadIdx.x == 0) ((uint_t*)ws)[0] = (s_cnt >= 160) ? 1u : 0u;
}

__global__ void prep_bias(const void* __restrict__ b0, const void* __restrict__ b1,
                          const void* __restrict__ b2, const void* __restrict__ b3,
                          const void* __restrict__ bsig, const void* __restrict__ brgb,
                          ushort_t* __restrict__ ws) {
  const int isbf = (int)((const uint_t*)ws)[0];
  int i = threadIdx.x;
  ws[OFF_B0 + i] = ldbf(b0, i, isbf);
  ws[OFF_B1 + i] = ldbf(b1, i, isbf);
  ws[OFF_B2 + i] = ldbf(b2, i, isbf);
  ws[OFF_B3 + i] = ldbf(b3, i, isbf);
  if (i == 0) ws[OFF_BSIG] = ldbf(bsig, 0, isbf);
  if (i < 3) ws[OFF_BRGB + i] = ldbf(brgb, i, isbf);
}

// weights -> 32x32x16 A-frags of W^T, tile order [kt][mt]
__global__ void prep_weights(const void* __restrict__ W0,
                             const void* __restrict__ W1,
                             const void* __restrict__ W2,
                             const void* __restrict__ W3,
                             const void* __restrict__ Wsig,
                             const void* __restrict__ Wrgb,
                             ushort_t* __restrict__ ws) {
  const int isbf = (int)((const uint_t*)ws)[0];
  int t = blockIdx.x * 256 + threadIdx.x;   // 432 tiles * 64 lanes = 27648
  if (t >= 432 * 64) return;
  int lane = t & 63;
  int tile = t >> 6;
  const void* src = nullptr;
  ushort_t* dst;
  int local, Ksrc = 256;
  bool head = false;
  if (tile < 32) { local = tile; src = W0; Ksrc = 47; dst = ws + OFF_W0 + (size_t)local * 512; }
  else if (tile < 160) { local = tile - 32;  src = W1; dst = ws + OFF_W1 + (size_t)local * 512; }
  else if (tile < 288) { local = tile - 160; src = W2; dst = ws + OFF_W2 + (size_t)local * 512; }
  else if (tile < 416) { local = tile - 288; src = W3; dst = ws + OFF_W3 + (size_t)local * 512; }
  else { local = tile - 416; head = true; dst = ws + OFF_WH + (size_t)local * 512; }
  int kt = head ? local : (local >> 3);
  int mt = head ? 0 : (local & 7);
  int n = mt * 32 + (lane & 31);         // out-col (A-frag m)
  int kb = kt * 16 + (lane >> 5) * 8;    // k base
  for (int j = 0; j < 8; ++j) {
    int k = kb + j;
    ushort_t v = 0;
    if (head) {
      if (n < 3) v = ldbf(Wrgb, (long)k * 3 + n, isbf);
      else if (n == 3) v = ldbf(Wsig, k, isbf);
    } else if (k < Ksrc) {
      v = ldbf(src, (long)k * 256 + n, isbf);
    }
    dst[lane * 8 + j] = v;
  }
}

__global__ void prep_planes(const void* __restrict__ fxy,
                            const void* __restrict__ fxz,
                            const void* __restrict__ fyz,
                            ushort_t* __restrict__ ws) {
  const int isbf = (int)((const uint_t*)ws)[0];
  int t = blockIdx.x * 256 + threadIdx.x;   // 3*16384 = 49152
  int plane = t >> 14, pos = t & 16383;
  const void* src = (plane == 0) ? fxy : (plane == 1) ? fxz : fyz;
  ushort_t* d = ws + OFF_PL + (size_t)plane * 131072 + (size_t)pos * 8;
  for (int r = 0; r < 8; ++r) d[r] = ldbf(src, (long)r * 16384 + pos, isbf);
}

// ------------------------------------------------------------------
// main: block = 256 thr / 4 waves / 64 points. Wave w covers out-cols
// [w*64, w*64+64) x all 64 points: acc[mi(2)][d(2)] f32x16 = 64 VGPRs,
// a[2]+b[2] = 16 -> ~95 live, fits the 128-reg cap of (256,4).
// D = W^T(A-frags, L2) x Act^T(B-frags, LDS). B reads are lane-sequential
// (conflict-free) with pure immediate offsets; n-redundancy of weight
// reads = 1 (round-7 evidence: 14 GB of L2 weight stream ~= 400 us was
// the wall; this halves it and removes the 4.6e7 LDS conflicts).
// ------------------------------------------------------------------
template <int KT>
__device__ __forceinline__ void mlp_layer(ushort_t* s_act,
                                          const ushort_t* __restrict__ wsW,
                                          const ushort_t* __restrict__ bias,
                                          int w, int lane) {
  f32x16 acc[2][2] = {};
  const int p31 = lane & 31;
  const int q2 = lane >> 5;
  const ushort_t* bbase = s_act + lane * 8;
  const ushort_t* abase = wsW + w * 1024 + lane * 8;
#pragma unroll 2
  for (int kt = 0; kt < KT; ++kt) {
    bf16x8 a[2], b[2];
#pragma unroll
    for (int mi = 0; mi < 2; ++mi) {
      union { uint4 u; bf16x8 v; } t;
      t.u = *(const uint4*)(abase + kt * 4096 + mi * 512);
      a[mi] = t.v;
    }
#pragma unroll
    for (int d = 0; d < 2; ++d) {
      union { uint4 u; bf16x8 v; } t;
      t.u = *(const uint4*)(bbase + d * 8192 + kt * 512);
      b[d] = t.v;
    }
#pragma unroll
    for (int mi = 0; mi < 2; ++mi)
#pragma unroll
      for (int d = 0; d < 2; ++d)
        acc[mi][d] = __builtin_amdgcn_mfma_f32_32x32x16_bf16(a[mi], b[d], acc[mi][d], 0, 0, 0);
  }
  __syncthreads();   // all waves done reading act
  // D: lane -> point p31 (within n-tile d), q2 selects col-half; reg quad rq
  // holds 4 consecutive cols  col = w*64 + mi*32 + rq*8 + q2*4 + {0..3}
  ushort_t* wbase = s_act + w * 2048 + p31 * 8 + q2 * 4;
#pragma unroll
  for (int mi = 0; mi < 2; ++mi) {
#pragma unroll
    for (int rq = 0; rq < 4; ++rq) {
      int col0 = w * 64 + mi * 32 + rq * 8 + q2 * 4;
      ushort4 bb = *(const ushort4*)(bias + col0);
      float bf0 = bf2f(bb.x), bf1 = bf2f(bb.y), bf2v = bf2f(bb.z), bf3 = bf2f(bb.w);
#pragma unroll
      for (int d = 0; d < 2; ++d) {
        const f32x16& A = acc[mi][d];
        float v0 = fmaxf(A[rq * 4 + 0] + bf0, 0.0f);
        float v1 = fmaxf(A[rq * 4 + 1] + bf1, 0.0f);
        float v2 = fmaxf(A[rq * 4 + 2] + bf2v, 0.0f);
        float v3 = fmaxf(A[rq * 4 + 3] + bf3, 0.0f);
        uint2 pk; pk.x = pk2bf(v0, v1); pk.y = pk2bf(v2, v3);
        *(uint2*)(wbase + d * 8192 + mi * 1024 + (rq >> 1) * 512 + (rq & 1) * 256) = pk;
      }
    }
  }
  __syncthreads();   // act ready for next layer
}

__global__ __launch_bounds__(256, 4)
void tensorf_main(const void* __restrict__ x,
                  const ushort_t* __restrict__ ws,
                  void* __restrict__ out) {
  __shared__ ushort_t s_act[2 * 16 * 512];   // 32 KB frag-native act buffer
  const int isbf = (int)((const uint_t*)ws)[0];
  const int tid = threadIdx.x;
  const int lane = tid & 63;
  const int wid = tid >> 6;        // 0..3
  const int blk = blockIdx.x;

  // ---- Phase A: features + PE into frag layout, cols 0..63 ----
  // 4 threads per point: s=0 gather+x; s=1: lvl 0,1; s=2: lvl 2,3; s=3: lvl 4,5+pad
  {
    int pl = tid >> 2;            // 0..63
    int s = tid & 3;
    long p = (long)blk * 64 + pl;
    float x0 = ldf(x, p * 3 + 0, isbf);
    float x1 = ldf(x, p * 3 + 1, isbf);
    float x2 = ldf(x, p * 3 + 2, isbf);
    if (s == 0) {
      int ix = (int)(((x0 + 1.0f) * 0.5f) * 127.0f);
      int iy = (int)(((x1 + 1.0f) * 0.5f) * 127.0f);
      int iz = (int)(((x2 + 1.0f) * 0.5f) * 127.0f);
      ix = ix < 0 ? 0 : (ix > 127 ? 127 : ix);
      iy = iy < 0 ? 0 : (iy > 127 ? 127 : iy);
      iz = iz < 0 ? 0 : (iz > 127 ? 127 : iz);
      union { uint4 u; ushort_t s[8]; } a, b, c;
      a.u = *(const uint4*)(ws + OFF_PL + (size_t)(iy * 128 + ix) * 8);
      b.u = *(const uint4*)(ws + OFF_PL + 131072 + (size_t)(iz * 128 + ix) * 8);
      c.u = *(const uint4*)(ws + OFF_PL + 262144 + (size_t)(iz * 128 + iy) * 8);
      union { uint4 u; uint_t w[4]; } f;
#pragma unroll
      for (int r = 0; r < 8; r += 2) {
        float f0 = bf2f(a.s[r]) + bf2f(b.s[r]) + bf2f(c.s[r]);
        float f1 = bf2f(a.s[r + 1]) + bf2f(b.s[r + 1]) + bf2f(c.s[r + 1]);
        f.w[r >> 1] = pk2bf(f0, f1);
      }
      *(uint4*)(s_act + fragaddr(pl, 0)) = f.u;      // cols 0..7 contiguous
      *(uint_t*)(s_act + fragaddr(pl, 8)) = pk2bf(x0, x1);
      s_act[fragaddr(pl, 10)] = f2bf(x2);
    } else if (s == 3) {
      float fx[3] = { x0, x1, x2 };
#pragma unroll
      for (int l = 4; l < 6; ++l) {
        float fr = (float)(1 << l);
        int k0 = 11 + l * 6;
#pragma unroll
        for (int dd = 0; dd < 3; ++dd) {
          float ang = fx[dd] * fr;
          s_act[fragaddr(pl, k0 + dd)]     = f2bf(__sinf(ang));
          s_act[fragaddr(pl, k0 + 3 + dd)] = f2bf(__cosf(ang));
        }
      }
      s_act[fragaddr(pl, 47)] = 0;
      *(uint4*)(s_act + fragaddr(pl, 48)) = uint4{0, 0, 0, 0};
      *(uint4*)(s_act + fragaddr(pl, 56)) = uint4{0, 0, 0, 0};
    } else {
      float fx[3] = { x0, x1, x2 };
#pragma unroll
      for (int li = 0; li < 2; ++li) {
        int l = (s - 1) * 2 + li;
        float fr = (float)(1 << l);
        int k0 = 11 + l * 6;
#pragma unroll
        for (int dd = 0; dd < 3; ++dd) {
          float ang = fx[dd] * fr;
          s_act[fragaddr(pl, k0 + dd)]     = f2bf(__sinf(ang));
          s_act[fragaddr(pl, k0 + 3 + dd)] = f2bf(__cosf(ang));
        }
      }
    }
  }
  __syncthreads();

  mlp_layer<4>(s_act, ws + OFF_W0, ws + OFF_B0, wid, lane);
  mlp_layer<16>(s_act, ws + OFF_W1, ws + OFF_B1, wid, lane);
  mlp_layer<16>(s_act, ws + OFF_W2, ws + OFF_B2, wid, lane);
  mlp_layer<16>(s_act, ws + OFF_W3, ws + OFF_B3, wid, lane);

  // ---- head: D = Wh^T(32x256, cols 0..3 real) x Act^T; waves 0,1 ----
  if (wid < 2) {
    f32x16 acc = {};
    const int p31 = lane & 31;
    const int q2 = lane >> 5;
    const ushort_t* hb = s_act + wid * 8192 + lane * 8;
    const ushort_t* wh = ws + OFF_WH + lane * 8;
#pragma unroll 4
    for (int kt = 0; kt < 16; ++kt) {
      union { uint4 u; bf16x8 v; } ta, tb;
      ta.u = *(const uint4*)(wh + kt * 512);
      tb.u = *(const uint4*)(hb + kt * 512);
      acc = __builtin_amdgcn_mfma_f32_32x32x16_bf16(ta.v, tb.v, acc, 0, 0, 0);
    }
    if (q2 == 0) {   // regs 0..3 = cols 0..3 = rgb0, rgb1, rgb2, sigma
      long pp = (long)blk * 64 + wid * 32 + p31;
      float br0 = bf2f(ws[OFF_BRGB + 0]), br1 = bf2f(ws[OFF_BRGB + 1]), br2 = bf2f(ws[OFF_BRGB + 2]);
      float bs = bf2f(ws[OFF_BSIG]);
      float z0 = acc[0] + br0, z1 = acc[1] + br1, z2 = acc[2] + br2;
      stf(out, pp * 3 + 0, isbf, 1.0f / (1.0f + __expf(-z0)));
      stf(out, pp * 3 + 1, isbf, 1.0f / (1.0f + __expf(-z1)));
      stf(out, pp * 3 + 2, isbf, 1.0f / (1.0f + __expf(-z2)));
      float zs = acc[3] + bs;
      float sp = (zs > 20.0f) ? zs : __logf(1.0f + __expf(zs));
      stf(out, (long)3 * NPTS + pp, isbf, sp);
    }
  }
}

extern "C" void kernel_launch(void* const* d_in, const int* in_sizes, int n_in,
                              void* d_out, int out_size, void* d_ws, size_t ws_size,
                              hipStream_t stream) {
  const void* x    = d_in[0];
  const void* fxy  = d_in[1];
  const void* fxz  = d_in[2];
  const void* fyz  = d_in[3];
  const void* W0   = d_in[4];
  const void* b0   = d_in[5];
  const void* W1   = d_in[6];
  const void* b1   = d_in[7];
  const void* W2   = d_in[8];
  const void* b2   = d_in[9];
  const void* W3   = d_in[10];
  const void* b3   = d_in[11];
  const void* Wsig = d_in[12];
  const void* bsig = d_in[13];
  const void* Wrgb = d_in[14];
  const void* brgb = d_in[15];
  ushort_t* ws = (ushort_t*)d_ws;

  hipLaunchKernelGGL(sniff_dtype, dim3(1), dim3(64), 0, stream, fxy, ws);
  hipLaunchKernelGGL(prep_bias, dim3(1), dim3(256), 0, stream,
                     b0, b1, b2, b3, bsig, brgb, ws);
  hipLaunchKernelGGL(prep_weights, dim3(108), dim3(256), 0, stream,
                     W0, W1, W2, W3, Wsig, Wrgb, ws);
  hipLaunchKernelGGL(prep_planes, dim3(192), dim3(256), 0, stream,
                     fxy, fxz, fyz, ws);
  hipLaunchKernelGGL(tensorf_main, dim3(16384), dim3(256), 0, stream,
                     x, ws, d_out);
}

// Round 9
// 554.187 us; speedup vs baseline: 1.7464x; 1.0976x over previous
//
#include <hip/hip_runtime.h>
#include <hip/hip_bf16.h>

typedef unsigned short ushort_t;
typedef unsigned int uint_t;

typedef __bf16 bf16x8 __attribute__((ext_vector_type(8)));
typedef float f32x4 __attribute__((ext_vector_type(4)));
typedef float f32x16 __attribute__((ext_vector_type(16)));

#define NPTS (1 << 20)

// ---- ws layout (ushort units) ----
// Weights stored as 32x32x16 MFMA A-fragments of W^T: tile = 32 out-cols (m)
// x 16 k; lane l: m = l&31, k = (l>>5)*8 + j. Tile order [kt][mt(8)].
#define OFF_FLAG 0        // uint flag: 1 = inputs bf16, 0 = fp32
#define OFF_B0   16
#define OFF_B1   272
#define OFF_B2   528
#define OFF_B3   784
#define OFF_BSIG 1040
#define OFF_BRGB 1041
#define OFF_W0   1056     // K=64 (47 padded): 4 kt x 8 mt = 32 tiles * 512
#define OFF_W1   17440    // K=256: 16 kt x 8 mt = 128 tiles * 512
#define OFF_W2   82976
#define OFF_W3   148512
#define OFF_WH   214048   // head: 16 kt x 1 mt (cols rgb0,rgb1,rgb2,sig,0..)
#define OFF_PL   222240   // transposed planes [plane][pos(16384)][rank(8)]

__device__ __forceinline__ float bf2f(ushort_t u) {
  union { uint_t i; float f; } c; c.i = ((uint_t)u) << 16; return c.f;
}
__device__ __forceinline__ ushort_t f2bf(float f) {
  union { float f; uint_t i; } c; c.f = f;
  uint_t x = c.i;
  return (ushort_t)((x + 0x7fffu + ((x >> 16) & 1u)) >> 16);
}
__device__ __forceinline__ uint_t pk2bf(float a, float b) {
  __hip_bfloat162 h = __float22bfloat162_rn(float2{a, b});
  union { __hip_bfloat162 h; uint_t u; } c; c.h = h; return c.u;
}
__device__ __forceinline__ float ldf(const void* p, long i, int isbf) {
  return isbf ? bf2f(((const ushort_t*)p)[i]) : ((const float*)p)[i];
}
__device__ __forceinline__ ushort_t ldbf(const void* p, long i, int isbf) {
  return isbf ? ((const ushort_t*)p)[i] : f2bf(((const float*)p)[i]);
}
__device__ __forceinline__ void stf(void* p, long i, int isbf, float v) {
  if (isbf) ((ushort_t*)p)[i] = f2bf(v);
  else      ((float*)p)[i] = v;
}

// Activation LDS layout = 32x32x16 B-fragment native (128 points = 4 n-tiles):
// element (point p, col k) -> frag(ntile=p>>5, kt=k>>4), lane = ((k>>3)&1)*32
// + (p&31), j = k&7.  frag stride 512 ushorts, ntile stride 8192.
__device__ __forceinline__ int fragaddr(int p, int k) {
  return ((p >> 5) << 13) + ((k >> 4) << 9) + (((k >> 3) & 1) << 8)
       + ((p & 31) << 3) + (k & 7);
}

// ------------------------------------------------------------------
__global__ void sniff_dtype(const void* __restrict__ f, ushort_t* __restrict__ ws) {
  __shared__ int s_cnt;
  if (threadIdx.x == 0) s_cnt = 0;
  __syncthreads();
  const ushort_t* u = (const ushort_t*)f;
  int c = 0;
  for (int j = 0; j < 4; ++j) {
    ushort_t v = u[(threadIdx.x * 4 + j) * 2];
    int e = (v >> 7) & 0xFF;
    if (e > 100 && e < 140) ++c;
  }
  atomicAdd(&s_cnt, c);
  __syncthreads();
  if (threadIdx.x == 0) ((uint_t*)ws)[0] = (s_cnt >= 160) ? 1u : 0u;
}

__global__ void prep_bias(const void* __restrict__ b0, const void* __restrict__ b1,
                          const void* __restrict__ b2, const void* __restrict__ b3,
                          const void* __restrict__ bsig, const void* __restrict__ brgb,
                          ushort_t* __restrict__ ws) {
  const int isbf = (int)((const uint_t*)ws)[0];
  int i = threadIdx.x;
  ws[OFF_B0 + i] = ldbf(b0, i, isbf);
  ws[OFF_B1 + i] = ldbf(b1, i, isbf);
  ws[OFF_B2 + i] = ldbf(b2, i, isbf);
  ws[OFF_B3 + i] = ldbf(b3, i, isbf);
  if (i == 0) ws[OFF_BSIG] = ldbf(bsig, 0, isbf);
  if (i < 3) ws[OFF_BRGB + i] = ldbf(brgb, i, isbf);
}

// weights -> 32x32x16 A-frags of W^T, tile order [kt][mt]
__global__ void prep_weights(const void* __restrict__ W0,
                             const void* __restrict__ W1,
                             const void* __restrict__ W2,
                             const void* __restrict__ W3,
                             const void* __restrict__ Wsig,
                             const void* __restrict__ Wrgb,
                             ushort_t* __restrict__ ws) {
  const int isbf = (int)((const uint_t*)ws)[0];
  int t = blockIdx.x * 256 + threadIdx.x;   // 432 tiles * 64 lanes = 27648
  if (t >= 432 * 64) return;
  int lane = t & 63;
  int tile = t >> 6;
  const void* src = nullptr;
  ushort_t* dst;
  int local, Ksrc = 256;
  bool head = false;
  if (tile < 32) { local = tile; src = W0; Ksrc = 47; dst = ws + OFF_W0 + (size_t)local * 512; }
  else if (tile < 160) { local = tile - 32;  src = W1; dst = ws + OFF_W1 + (size_t)local * 512; }
  else if (tile < 288) { local = tile - 160; src = W2; dst = ws + OFF_W2 + (size_t)local * 512; }
  else if (tile < 416) { local = tile - 288; src = W3; dst = ws + OFF_W3 + (size_t)local * 512; }
  else { local = tile - 416; head = true; dst = ws + OFF_WH + (size_t)local * 512; }
  int kt = head ? local : (local >> 3);
  int mt = head ? 0 : (local & 7);
  int n = mt * 32 + (lane & 31);         // out-col (A-frag m)
  int kb = kt * 16 + (lane >> 5) * 8;    // k base
  for (int j = 0; j < 8; ++j) {
    int k = kb + j;
    ushort_t v = 0;
    if (head) {
      if (n < 3) v = ldbf(Wrgb, (long)k * 3 + n, isbf);
      else if (n == 3) v = ldbf(Wsig, k, isbf);
    } else if (k < Ksrc) {
      v = ldbf(src, (long)k * 256 + n, isbf);
    }
    dst[lane * 8 + j] = v;
  }
}

__global__ void prep_planes(const void* __restrict__ fxy,
                            const void* __restrict__ fxz,
                            const void* __restrict__ fyz,
                            ushort_t* __restrict__ ws) {
  const int isbf = (int)((const uint_t*)ws)[0];
  int t = blockIdx.x * 256 + threadIdx.x;   // 3*16384 = 49152
  int plane = t >> 14, pos = t & 16383;
  const void* src = (plane == 0) ? fxy : (plane == 1) ? fxz : fyz;
  ushort_t* d = ws + OFF_PL + (size_t)plane * 131072 + (size_t)pos * 8;
  for (int r = 0; r < 8; ++r) d[r] = ldbf(src, (long)r * 16384 + pos, isbf);
}

// ------------------------------------------------------------------
// main: block = 512 thr / 8 waves / 128 points. Wave w covers out-cols
// [w*32, w*32+32) x all 128 points: acc[4] f32x16 = 64 AGPRs;
// per kt: ONE global A-load (prefetched one kt ahead, peeled loop),
// 4 LDS B-reads (pure immediates), 4 MFMAs.
// Round-8 evidence: 64-pt blocks re-streamed 8.6 GB of weights from L2
// (~250 us > 177 us MFMA floor). 128-pt blocks halve that; 4 MFMA per
// global load + explicit prefetch hides L2 latency.
// ------------------------------------------------------------------
template <int KT>
__device__ __forceinline__ void mlp_layer(ushort_t* s_act,
                                          const ushort_t* __restrict__ wsW,
                                          const ushort_t* __restrict__ bias,
                                          int w, int lane) {
  f32x16 acc[4] = {};
  const int p31 = lane & 31;
  const int q2 = lane >> 5;
  const ushort_t* bbase = s_act + lane * 8;
  const ushort_t* abase = wsW + w * 512 + lane * 8;
  union { uint4 u; bf16x8 v; } a_cur, a_nxt;
  a_cur.u = *(const uint4*)(abase);
#pragma unroll 1
  for (int kt = 0; kt < KT - 1; ++kt) {
    a_nxt.u = *(const uint4*)(abase + (kt + 1) * 4096);
    bf16x8 b[4];
#pragma unroll
    for (int d = 0; d < 4; ++d) {
      union { uint4 u; bf16x8 v; } t;
      t.u = *(const uint4*)(bbase + d * 8192 + kt * 512);
      b[d] = t.v;
    }
#pragma unroll
    for (int d = 0; d < 4; ++d)
      acc[d] = __builtin_amdgcn_mfma_f32_32x32x16_bf16(a_cur.v, b[d], acc[d], 0, 0, 0);
    a_cur = a_nxt;
  }
  {  // last kt, no prefetch
    const int kt = KT - 1;
    bf16x8 b[4];
#pragma unroll
    for (int d = 0; d < 4; ++d) {
      union { uint4 u; bf16x8 v; } t;
      t.u = *(const uint4*)(bbase + d * 8192 + kt * 512);
      b[d] = t.v;
    }
#pragma unroll
    for (int d = 0; d < 4; ++d)
      acc[d] = __builtin_amdgcn_mfma_f32_32x32x16_bf16(a_cur.v, b[d], acc[d], 0, 0, 0);
  }
  __syncthreads();   // all waves done reading act
  // D: lane -> point p31 (in n-tile d); reg quad rq holds 4 consecutive cols
  // col = w*32 + rq*8 + q2*4 + {0..3}
  ushort_t* wbase = s_act + w * 1024 + p31 * 8 + q2 * 4;
#pragma unroll
  for (int rq = 0; rq < 4; ++rq) {
    int col0 = w * 32 + rq * 8 + q2 * 4;
    ushort4 bb = *(const ushort4*)(bias + col0);
    float bf0 = bf2f(bb.x), bf1 = bf2f(bb.y), bf2v = bf2f(bb.z), bf3 = bf2f(bb.w);
#pragma unroll
    for (int d = 0; d < 4; ++d) {
      const f32x16& A = acc[d];
      float v0 = fmaxf(A[rq * 4 + 0] + bf0, 0.0f);
      float v1 = fmaxf(A[rq * 4 + 1] + bf1, 0.0f);
      float v2 = fmaxf(A[rq * 4 + 2] + bf2v, 0.0f);
      float v3 = fmaxf(A[rq * 4 + 3] + bf3, 0.0f);
      uint2 pk; pk.x = pk2bf(v0, v1); pk.y = pk2bf(v2, v3);
      *(uint2*)(wbase + d * 8192 + (rq >> 1) * 512 + (rq & 1) * 256) = pk;
    }
  }
  __syncthreads();   // act ready for next layer
}

__global__ __launch_bounds__(512, 4)
void tensorf_main(const void* __restrict__ x,
                  const ushort_t* __restrict__ ws,
                  void* __restrict__ out) {
  __shared__ ushort_t s_act[4 * 16 * 512];   // 64 KB frag-native act (128 pts)
  const int isbf = (int)((const uint_t*)ws)[0];
  const int tid = threadIdx.x;
  const int lane = tid & 63;
  const int wid = tid >> 6;        // 0..7
  const int blk = blockIdx.x;

  // ---- Phase A: features + PE into frag layout, cols 0..63 ----
  // 4 threads per point: s=0 gather+x; s=1: lvl 0,1; s=2: lvl 2,3; s=3: lvl 4,5+pad
  {
    int pl = tid >> 2;            // 0..127
    int s = tid & 3;
    long p = (long)blk * 128 + pl;
    float x0 = ldf(x, p * 3 + 0, isbf);
    float x1 = ldf(x, p * 3 + 1, isbf);
    float x2 = ldf(x, p * 3 + 2, isbf);
    if (s == 0) {
      int ix = (int)(((x0 + 1.0f) * 0.5f) * 127.0f);
      int iy = (int)(((x1 + 1.0f) * 0.5f) * 127.0f);
      int iz = (int)(((x2 + 1.0f) * 0.5f) * 127.0f);
      ix = ix < 0 ? 0 : (ix > 127 ? 127 : ix);
      iy = iy < 0 ? 0 : (iy > 127 ? 127 : iy);
      iz = iz < 0 ? 0 : (iz > 127 ? 127 : iz);
      union { uint4 u; ushort_t s[8]; } a, b, c;
      a.u = *(const uint4*)(ws + OFF_PL + (size_t)(iy * 128 + ix) * 8);
      b.u = *(const uint4*)(ws + OFF_PL + 131072 + (size_t)(iz * 128 + ix) * 8);
      c.u = *(const uint4*)(ws + OFF_PL + 262144 + (size_t)(iz * 128 + iy) * 8);
      union { uint4 u; uint_t w[4]; } f;
#pragma unroll
      for (int r = 0; r < 8; r += 2) {
        float f0 = bf2f(a.s[r]) + bf2f(b.s[r]) + bf2f(c.s[r]);
        float f1 = bf2f(a.s[r + 1]) + bf2f(b.s[r + 1]) + bf2f(c.s[r + 1]);
        f.w[r >> 1] = pk2bf(f0, f1);
      }
      *(uint4*)(s_act + fragaddr(pl, 0)) = f.u;      // cols 0..7 contiguous
      *(uint_t*)(s_act + fragaddr(pl, 8)) = pk2bf(x0, x1);
      s_act[fragaddr(pl, 10)] = f2bf(x2);
    } else if (s == 3) {
      float fx[3] = { x0, x1, x2 };
#pragma unroll
      for (int l = 4; l < 6; ++l) {
        float fr = (float)(1 << l);
        int k0 = 11 + l * 6;
#pragma unroll
        for (int dd = 0; dd < 3; ++dd) {
          float ang = fx[dd] * fr;
          s_act[fragaddr(pl, k0 + dd)]     = f2bf(__sinf(ang));
          s_act[fragaddr(pl, k0 + 3 + dd)] = f2bf(__cosf(ang));
        }
      }
      s_act[fragaddr(pl, 47)] = 0;
      *(uint4*)(s_act + fragaddr(pl, 48)) = uint4{0, 0, 0, 0};
      *(uint4*)(s_act + fragaddr(pl, 56)) = uint4{0, 0, 0, 0};
    } else {
      float fx[3] = { x0, x1, x2 };
#pragma unroll
      for (int li = 0; li < 2; ++li) {
        int l = (s - 1) * 2 + li;
        float fr = (float)(1 << l);
        int k0 = 11 + l * 6;
#pragma unroll
        for (int dd = 0; dd < 3; ++dd) {
          float ang = fx[dd] * fr;
          s_act[fragaddr(pl, k0 + dd)]     = f2bf(__sinf(ang));
          s_act[fragaddr(pl, k0 + 3 + dd)] = f2bf(__cosf(ang));
        }
      }
    }
  }
  __syncthreads();

  mlp_layer<4>(s_act, ws + OFF_W0, ws + OFF_B0, wid, lane);
  mlp_layer<16>(s_act, ws + OFF_W1, ws + OFF_B1, wid, lane);
  mlp_layer<16>(s_act, ws + OFF_W2, ws + OFF_B2, wid, lane);
  mlp_layer<16>(s_act, ws + OFF_W3, ws + OFF_B3, wid, lane);

  // ---- head: D = Wh^T(32x256, cols 0..3 real) x Act^T; waves 0..3 ----
  if (wid < 4) {
    f32x16 acc = {};
    const int p31 = lane & 31;
    const int q2 = lane >> 5;
    const ushort_t* hb = s_act + wid * 8192 + lane * 8;
    const ushort_t* wh = ws + OFF_WH + lane * 8;
#pragma unroll 4
    for (int kt = 0; kt < 16; ++kt) {
      union { uint4 u; bf16x8 v; } ta, tb;
      ta.u = *(const uint4*)(wh + kt * 512);
      tb.u = *(const uint4*)(hb + kt * 512);
      acc = __builtin_amdgcn_mfma_f32_32x32x16_bf16(ta.v, tb.v, acc, 0, 0, 0);
    }
    if (q2 == 0) {   // regs 0..3 = cols 0..3 = rgb0, rgb1, rgb2, sigma
      long pp = (long)blk * 128 + wid * 32 + p31;
      float br0 = bf2f(ws[OFF_BRGB + 0]), br1 = bf2f(ws[OFF_BRGB + 1]), br2 = bf2f(ws[OFF_BRGB + 2]);
      float bs = bf2f(ws[OFF_BSIG]);
      float z0 = acc[0] + br0, z1 = acc[1] + br1, z2 = acc[2] + br2;
      stf(out, pp * 3 + 0, isbf, 1.0f / (1.0f + __expf(-z0)));
      stf(out, pp * 3 + 1, isbf, 1.0f / (1.0f + __expf(-z1)));
      stf(out, pp * 3 + 2, isbf, 1.0f / (1.0f + __expf(-z2)));
      float zs = acc[3] + bs;
      float sp = (zs > 20.0f) ? zs : __logf(1.0f + __expf(zs));
      stf(out, (long)3 * NPTS + pp, isbf, sp);
    }
  }
}

extern "C" void kernel_launch(void* const* d_in, const int* in_sizes, int n_in,
                              void* d_out, int out_size, void* d_ws, size_t ws_size,
                              hipStream_t stream) {
  const void* x    = d_in[0];
  const void* fxy  = d_in[1];
  const void* fxz  = d_in[2];
  const void* fyz  = d_in[3];
  const void* W0   = d_in[4];
  const void* b0   = d_in[5];
  const void* W1   = d_in[6];
  const void* b1   = d_in[7];
  const void* W2   = d_in[8];
  const void* b2   = d_in[9];
  const void* W3   = d_in[10];
  const void* b3   = d_in[11];
  const void* Wsig = d_in[12];
  const void* bsig = d_in[13];
  const void* Wrgb = d_in[14];
  const void* brgb = d_in[15];
  ushort_t* ws = (ushort_t*)d_ws;

  hipLaunchKernelGGL(sniff_dtype, dim3(1), dim3(64), 0, stream, fxy, ws);
  hipLaunchKernelGGL(prep_bias, dim3(1), dim3(256), 0, stream,
                     b0, b1, b2, b3, bsig, brgb, ws);
  hipLaunchKernelGGL(prep_weights, dim3(108), dim3(256), 0, stream,
                     W0, W1, W2, W3, Wsig, Wrgb, ws);
  hipLaunchKernelGGL(prep_planes, dim3(192), dim3(256), 0, stream,
                     fxy, fxz, fyz, ws);
  hipLaunchKernelGGL(tensorf_main, dim3(8192), dim3(512), 0, stream,
                     x, ws, d_out);
}

// Round 10
// 536.177 us; speedup vs baseline: 1.8051x; 1.0336x over previous
//
#include <hip/hip_runtime.h>
#include <hip/hip_bf16.h>

typedef unsigned short ushort_t;
typedef unsigned int uint_t;

typedef __bf16 bf16x8 __attribute__((ext_vector_type(8)));
typedef float f32x4 __attribute__((ext_vector_type(4)));
typedef float f32x16 __attribute__((ext_vector_type(16)));

#define NPTS (1 << 20)

// ---- ws layout (ushort units) ----
// Weights stored as 32x32x16 MFMA A-fragments of W^T: tile = 32 out-cols (m)
// x 16 k; lane l: m = l&31, k = (l>>5)*8 + j. Tile order [kt][mt(8)].
#define OFF_FLAG 0        // uint flag: 1 = inputs bf16, 0 = fp32
#define OFF_B0   16
#define OFF_B1   272
#define OFF_B2   528
#define OFF_B3   784
#define OFF_BSIG 1040
#define OFF_BRGB 1041
#define OFF_W0   1056     // K=64 (47 padded): 4 kt x 8 mt = 32 tiles * 512
#define OFF_W1   17440    // K=256: 16 kt x 8 mt = 128 tiles * 512
#define OFF_W2   82976
#define OFF_W3   148512
#define OFF_WH   214048   // head: 16 kt x 1 mt (cols rgb0,rgb1,rgb2,sig,0..)
#define OFF_PL   222240   // transposed planes [plane][pos(16384)][rank(8)]

__device__ __forceinline__ float bf2f(ushort_t u) {
  union { uint_t i; float f; } c; c.i = ((uint_t)u) << 16; return c.f;
}
__device__ __forceinline__ ushort_t f2bf(float f) {
  union { float f; uint_t i; } c; c.f = f;
  uint_t x = c.i;
  return (ushort_t)((x + 0x7fffu + ((x >> 16) & 1u)) >> 16);
}
__device__ __forceinline__ uint_t pk2bf(float a, float b) {
  __hip_bfloat162 h = __float22bfloat162_rn(float2{a, b});
  union { __hip_bfloat162 h; uint_t u; } c; c.h = h; return c.u;
}
__device__ __forceinline__ float ldf(const void* p, long i, int isbf) {
  return isbf ? bf2f(((const ushort_t*)p)[i]) : ((const float*)p)[i];
}
__device__ __forceinline__ ushort_t ldbf(const void* p, long i, int isbf) {
  return isbf ? ((const ushort_t*)p)[i] : f2bf(((const float*)p)[i]);
}
__device__ __forceinline__ void stf(void* p, long i, int isbf, float v) {
  if (isbf) ((ushort_t*)p)[i] = f2bf(v);
  else      ((float*)p)[i] = v;
}

// Activation LDS layout = 32x32x16 B-fragment native (128 points = 4 n-tiles):
// element (point p, col k) -> frag(ntile=p>>5, kt=k>>4), lane = ((k>>3)&1)*32
// + (p&31), j = k&7.  frag stride 512 ushorts, ntile stride 8192.
__device__ __forceinline__ int fragaddr(int p, int k) {
  return ((p >> 5) << 13) + ((k >> 4) << 9) + (((k >> 3) & 1) << 8)
       + ((p & 31) << 3) + (k & 7);
}

// ------------------------------------------------------------------
__global__ void sniff_dtype(const void* __restrict__ f, ushort_t* __restrict__ ws) {
  __shared__ int s_cnt;
  if (threadIdx.x == 0) s_cnt = 0;
  __syncthreads();
  const ushort_t* u = (const ushort_t*)f;
  int c = 0;
  for (int j = 0; j < 4; ++j) {
    ushort_t v = u[(threadIdx.x * 4 + j) * 2];
    int e = (v >> 7) & 0xFF;
    if (e > 100 && e < 140) ++c;
  }
  atomicAdd(&s_cnt, c);
  __syncthreads();
  if (threadIdx.x == 0) ((uint_t*)ws)[0] = (s_cnt >= 160) ? 1u : 0u;
}

__global__ void prep_bias(const void* __restrict__ b0, const void* __restrict__ b1,
                          const void* __restrict__ b2, const void* __restrict__ b3,
                          const void* __restrict__ bsig, const void* __restrict__ brgb,
                          ushort_t* __restrict__ ws) {
  const int isbf = (int)((const uint_t*)ws)[0];
  int i = threadIdx.x;
  ws[OFF_B0 + i] = ldbf(b0, i, isbf);
  ws[OFF_B1 + i] = ldbf(b1, i, isbf);
  ws[OFF_B2 + i] = ldbf(b2, i, isbf);
  ws[OFF_B3 + i] = ldbf(b3, i, isbf);
  if (i == 0) ws[OFF_BSIG] = ldbf(bsig, 0, isbf);
  if (i < 3) ws[OFF_BRGB + i] = ldbf(brgb, i, isbf);
}

// weights -> 32x32x16 A-frags of W^T, tile order [kt][mt]
__global__ void prep_weights(const void* __restrict__ W0,
                             const void* __restrict__ W1,
                             const void* __restrict__ W2,
                             const void* __restrict__ W3,
                             const void* __restrict__ Wsig,
                             const void* __restrict__ Wrgb,
                             ushort_t* __restrict__ ws) {
  const int isbf = (int)((const uint_t*)ws)[0];
  int t = blockIdx.x * 256 + threadIdx.x;   // 432 tiles * 64 lanes = 27648
  if (t >= 432 * 64) return;
  int lane = t & 63;
  int tile = t >> 6;
  const void* src = nullptr;
  ushort_t* dst;
  int local, Ksrc = 256;
  bool head = false;
  if (tile < 32) { local = tile; src = W0; Ksrc = 47; dst = ws + OFF_W0 + (size_t)local * 512; }
  else if (tile < 160) { local = tile - 32;  src = W1; dst = ws + OFF_W1 + (size_t)local * 512; }
  else if (tile < 288) { local = tile - 160; src = W2; dst = ws + OFF_W2 + (size_t)local * 512; }
  else if (tile < 416) { local = tile - 288; src = W3; dst = ws + OFF_W3 + (size_t)local * 512; }
  else { local = tile - 416; head = true; dst = ws + OFF_WH + (size_t)local * 512; }
  int kt = head ? local : (local >> 3);
  int mt = head ? 0 : (local & 7);
  int n = mt * 32 + (lane & 31);         // out-col (A-frag m)
  int kb = kt * 16 + (lane >> 5) * 8;    // k base
  for (int j = 0; j < 8; ++j) {
    int k = kb + j;
    ushort_t v = 0;
    if (head) {
      if (n < 3) v = ldbf(Wrgb, (long)k * 3 + n, isbf);
      else if (n == 3) v = ldbf(Wsig, k, isbf);
    } else if (k < Ksrc) {
      v = ldbf(src, (long)k * 256 + n, isbf);
    }
    dst[lane * 8 + j] = v;
  }
}

__global__ void prep_planes(const void* __restrict__ fxy,
                            const void* __restrict__ fxz,
                            const void* __restrict__ fyz,
                            ushort_t* __restrict__ ws) {
  const int isbf = (int)((const uint_t*)ws)[0];
  int t = blockIdx.x * 256 + threadIdx.x;   // 3*16384 = 49152
  int plane = t >> 14, pos = t & 16383;
  const void* src = (plane == 0) ? fxy : (plane == 1) ? fxz : fyz;
  ushort_t* d = ws + OFF_PL + (size_t)plane * 131072 + (size_t)pos * 8;
  for (int r = 0; r < 8; ++r) d[r] = ldbf(src, (long)r * 16384 + pos, isbf);
}

// ------------------------------------------------------------------
// main: block = 256 thr / 4 waves / 128 points, 2 waves/SIMD (256 regs
// per wave via __launch_bounds__(256,2)). Wave w covers out-cols
// [w*64, w*64+64) (2 m-tiles) x all 128 points (4 n-tiles):
// acc[2][4] f32x16 = 128 AGPRs. Per kt: 2 global A-loads + 4 LDS
// B-reads + 8 MFMAs (256 matrix-cycles). K-loop is manually unroll-2
// ping-ponged (a0/b0 vs a1/b1) so every load is issued one kt ahead
// of its MFMAs with zero register movs.
// Round-9 evidence: 1m x 4n tiling made every wave re-read the full
// act tile -> 17.8 GB of ds_read_b128 (~350 us at measured b128 rate)
// > 218 us MFMA floor. 2m-tiles/wave halves LDS reads; L2 weight
// traffic unchanged (4.5 GB); MFMA becomes the binding resource.
// Last-iteration prefetches read 1 tile past the layer (A: next ws
// region, valid; B: past the 64 KB LDS alloc -> HW returns 0) and are
// never consumed.
// ------------------------------------------------------------------
template <int KT>
__device__ __forceinline__ void mlp_layer(ushort_t* s_act,
                                          const ushort_t* __restrict__ wsW,
                                          const ushort_t* __restrict__ bias,
                                          int w, int lane) {
  f32x16 acc[2][4] = {};
  const int p31 = lane & 31;
  const int q2 = lane >> 5;
  const ushort_t* bptr = s_act + lane * 8;                  // + d*8192 + kt*512
  const ushort_t* aptr = wsW + (w * 2) * 512 + lane * 8;    // + mi*512 + kt*4096
  union U { uint4 u; bf16x8 v; };
  U a0[2], a1[2], b0[4], b1[4];
#pragma unroll
  for (int mi = 0; mi < 2; ++mi) a0[mi].u = *(const uint4*)(aptr + mi * 512);
#pragma unroll
  for (int d = 0; d < 4; ++d) b0[d].u = *(const uint4*)(bptr + d * 8192);
#pragma unroll 1
  for (int kt = 0; kt < KT; kt += 2) {
    // stage 0: prefetch kt+1 into a1/b1, compute kt from a0/b0
#pragma unroll
    for (int mi = 0; mi < 2; ++mi) a1[mi].u = *(const uint4*)(aptr + 4096 + mi * 512);
#pragma unroll
    for (int d = 0; d < 4; ++d) b1[d].u = *(const uint4*)(bptr + 512 + d * 8192);
#pragma unroll
    for (int mi = 0; mi < 2; ++mi)
#pragma unroll
      for (int d = 0; d < 4; ++d)
        acc[mi][d] = __builtin_amdgcn_mfma_f32_32x32x16_bf16(a0[mi].v, b0[d].v, acc[mi][d], 0, 0, 0);
    // stage 1: prefetch kt+2 into a0/b0, compute kt+1 from a1/b1
    aptr += 8192;   // 2 kt of A tiles (8 tiles * 512 ushorts * 2)
    bptr += 1024;   // 2 kt of B frags (512 ushorts * 2)
#pragma unroll
    for (int mi = 0; mi < 2; ++mi) a0[mi].u = *(const uint4*)(aptr + mi * 512);
#pragma unroll
    for (int d = 0; d < 4; ++d) b0[d].u = *(const uint4*)(bptr + d * 8192);
#pragma unroll
    for (int mi = 0; mi < 2; ++mi)
#pragma unroll
      for (int d = 0; d < 4; ++d)
        acc[mi][d] = __builtin_amdgcn_mfma_f32_32x32x16_bf16(a1[mi].v, b1[d].v, acc[mi][d], 0, 0, 0);
  }
  __syncthreads();   // all waves done reading act
  // D: lane -> point p31 (in n-tile d); reg quad rq = 4 consecutive cols
  // col = w*64 + mi*32 + rq*8 + q2*4 + {0..3}
  ushort_t* wbase = s_act + w * 2048 + p31 * 8 + q2 * 4;
#pragma unroll
  for (int mi = 0; mi < 2; ++mi) {
#pragma unroll
    for (int rq = 0; rq < 4; ++rq) {
      int col0 = w * 64 + mi * 32 + rq * 8 + q2 * 4;
      ushort4 bb = *(const ushort4*)(bias + col0);
      float bf0 = bf2f(bb.x), bf1 = bf2f(bb.y), bf2v = bf2f(bb.z), bf3 = bf2f(bb.w);
#pragma unroll
      for (int d = 0; d < 4; ++d) {
        const f32x16& A = acc[mi][d];
        float v0 = fmaxf(A[rq * 4 + 0] + bf0, 0.0f);
        float v1 = fmaxf(A[rq * 4 + 1] + bf1, 0.0f);
        float v2 = fmaxf(A[rq * 4 + 2] + bf2v, 0.0f);
        float v3 = fmaxf(A[rq * 4 + 3] + bf3, 0.0f);
        uint2 pk; pk.x = pk2bf(v0, v1); pk.y = pk2bf(v2, v3);
        *(uint2*)(wbase + d * 8192 + mi * 1024 + (rq >> 1) * 512 + (rq & 1) * 256) = pk;
      }
    }
  }
  __syncthreads();   // act ready for next layer
}

__global__ __launch_bounds__(256, 2)
void tensorf_main(const void* __restrict__ x,
                  const ushort_t* __restrict__ ws,
                  void* __restrict__ out) {
  __shared__ ushort_t s_act[4 * 16 * 512];   // 64 KB frag-native act (128 pts)
  const int isbf = (int)((const uint_t*)ws)[0];
  const int tid = threadIdx.x;
  const int lane = tid & 63;
  const int wid = tid >> 6;        // 0..3
  const int blk = blockIdx.x;

  // ---- Phase A: features + PE into frag layout, cols 0..63 ----
  // 2 threads per point: s=0 gather + x + pad + trig lvl 4,5; s=1 trig lvl 0..3
  {
    int pl = tid >> 1;            // 0..127
    int s = tid & 1;
    long p = (long)blk * 128 + pl;
    float x0 = ldf(x, p * 3 + 0, isbf);
    float x1 = ldf(x, p * 3 + 1, isbf);
    float x2 = ldf(x, p * 3 + 2, isbf);
    float fx[3] = { x0, x1, x2 };
    if (s == 0) {
      int ix = (int)(((x0 + 1.0f) * 0.5f) * 127.0f);
      int iy = (int)(((x1 + 1.0f) * 0.5f) * 127.0f);
      int iz = (int)(((x2 + 1.0f) * 0.5f) * 127.0f);
      ix = ix < 0 ? 0 : (ix > 127 ? 127 : ix);
      iy = iy < 0 ? 0 : (iy > 127 ? 127 : iy);
      iz = iz < 0 ? 0 : (iz > 127 ? 127 : iz);
      union { uint4 u; ushort_t s[8]; } a, b, c;
      a.u = *(const uint4*)(ws + OFF_PL + (size_t)(iy * 128 + ix) * 8);
      b.u = *(const uint4*)(ws + OFF_PL + 131072 + (size_t)(iz * 128 + ix) * 8);
      c.u = *(const uint4*)(ws + OFF_PL + 262144 + (size_t)(iz * 128 + iy) * 8);
      union { uint4 u; uint_t w[4]; } f;
#pragma unroll
      for (int r = 0; r < 8; r += 2) {
        float f0 = bf2f(a.s[r]) + bf2f(b.s[r]) + bf2f(c.s[r]);
        float f1 = bf2f(a.s[r + 1]) + bf2f(b.s[r + 1]) + bf2f(c.s[r + 1]);
        f.w[r >> 1] = pk2bf(f0, f1);
      }
      *(uint4*)(s_act + fragaddr(pl, 0)) = f.u;      // cols 0..7 contiguous
      *(uint_t*)(s_act + fragaddr(pl, 8)) = pk2bf(x0, x1);
      s_act[fragaddr(pl, 10)] = f2bf(x2);
#pragma unroll
      for (int l = 4; l < 6; ++l) {
        float fr = (float)(1 << l);
        int k0 = 11 + l * 6;
#pragma unroll
        for (int dd = 0; dd < 3; ++dd) {
          float ang = fx[dd] * fr;
          s_act[fragaddr(pl, k0 + dd)]     = f2bf(__sinf(ang));
          s_act[fragaddr(pl, k0 + 3 + dd)] = f2bf(__cosf(ang));
        }
      }
      s_act[fragaddr(pl, 47)] = 0;
      *(uint4*)(s_act + fragaddr(pl, 48)) = uint4{0, 0, 0, 0};
      *(uint4*)(s_act + fragaddr(pl, 56)) = uint4{0, 0, 0, 0};
    } else {
#pragma unroll
      for (int l = 0; l < 4; ++l) {
        float fr = (float)(1 << l);
        int k0 = 11 + l * 6;
#pragma unroll
        for (int dd = 0; dd < 3; ++dd) {
          float ang = fx[dd] * fr;
          s_act[fragaddr(pl, k0 + dd)]     = f2bf(__sinf(ang));
          s_act[fragaddr(pl, k0 + 3 + dd)] = f2bf(__cosf(ang));
        }
      }
    }
  }
  __syncthreads();

  mlp_layer<4>(s_act, ws + OFF_W0, ws + OFF_B0, wid, lane);
  mlp_layer<16>(s_act, ws + OFF_W1, ws + OFF_B1, wid, lane);
  mlp_layer<16>(s_act, ws + OFF_W2, ws + OFF_B2, wid, lane);
  mlp_layer<16>(s_act, ws + OFF_W3, ws + OFF_B3, wid, lane);

  // ---- head: D = Wh^T(32x256, cols 0..3 real) x Act^T; wave w = n-tile w ----
  {
    f32x16 acc = {};
    const int p31 = lane & 31;
    const int q2 = lane >> 5;
    const ushort_t* hb = s_act + wid * 8192 + lane * 8;
    const ushort_t* wh = ws + OFF_WH + lane * 8;
#pragma unroll 4
    for (int kt = 0; kt < 16; ++kt) {
      union { uint4 u; bf16x8 v; } ta, tb;
      ta.u = *(const uint4*)(wh + kt * 512);
      tb.u = *(const uint4*)(hb + kt * 512);
      acc = __builtin_amdgcn_mfma_f32_32x32x16_bf16(ta.v, tb.v, acc, 0, 0, 0);
    }
    if (q2 == 0) {   // regs 0..3 = cols 0..3 = rgb0, rgb1, rgb2, sigma
      long pp = (long)blk * 128 + wid * 32 + p31;
      float br0 = bf2f(ws[OFF_BRGB + 0]), br1 = bf2f(ws[OFF_BRGB + 1]), br2 = bf2f(ws[OFF_BRGB + 2]);
      float bs = bf2f(ws[OFF_BSIG]);
      float z0 = acc[0] + br0, z1 = acc[1] + br1, z2 = acc[2] + br2;
      stf(out, pp * 3 + 0, isbf, 1.0f / (1.0f + __expf(-z0)));
      stf(out, pp * 3 + 1, isbf, 1.0f / (1.0f + __expf(-z1)));
      stf(out, pp * 3 + 2, isbf, 1.0f / (1.0f + __expf(-z2)));
      float zs = acc[3] + bs;
      float sp = (zs > 20.0f) ? zs : __logf(1.0f + __expf(zs));
      stf(out, (long)3 * NPTS + pp, isbf, sp);
    }
  }
}

extern "C" void kernel_launch(void* const* d_in, const int* in_sizes, int n_in,
                              void* d_out, int out_size, void* d_ws, size_t ws_size,
                              hipStream_t stream) {
  const void* x    = d_in[0];
  const void* fxy  = d_in[1];
  const void* fxz  = d_in[2];
  const void* fyz  = d_in[3];
  const void* W0   = d_in[4];
  const void* b0   = d_in[5];
  const void* W1   = d_in[6];
  const void* b1   = d_in[7];
  const void* W2   = d_in[8];
  const void* b2   = d_in[9];
  const void* W3   = d_in[10];
  const void* b3   = d_in[11];
  const void* Wsig = d_in[12];
  const void* bsig = d_in[13];
  const void* Wrgb = d_in[14];
  const void* brgb = d_in[15];
  ushort_t* ws = (ushort_t*)d_ws;

  hipLaunchKernelGGL(sniff_dtype, dim3(1), dim3(64), 0, stream, fxy, ws);
  hipLaunchKernelGGL(prep_bias, dim3(1), dim3(256), 0, stream,
                     b0, b1, b2, b3, bsig, brgb, ws);
  hipLaunchKernelGGL(prep_weights, dim3(108), dim3(256), 0, stream,
                     W0, W1, W2, W3, Wsig, Wrgb, ws);
  hipLaunchKernelGGL(prep_planes, dim3(192), dim3(256), 0, stream,
                     fxy, fxz, fyz, ws);
  hipLaunchKernelGGL(tensorf_main, dim3(8192), dim3(256), 0, stream,
                     x, ws, d_out);
}

// Round 11
// 505.072 us; speedup vs baseline: 1.9163x; 1.0616x over previous
//
#include <hip/hip_runtime.h>
#include <hip/hip_bf16.h>

typedef unsigned short ushort_t;
typedef unsigned int uint_t;

typedef __bf16 bf16x8 __attribute__((ext_vector_type(8)));
typedef float f32x4 __attribute__((ext_vector_type(4)));
typedef float f32x16 __attribute__((ext_vector_type(16)));

#define NPTS (1 << 20)

// ---- ws layout (ushort units) ----
// Weights stored as 32x32x16 MFMA A-fragments of W^T: tile = 32 out-cols (m)
// x 16 k; lane l: m = l&31, k = (l>>5)*8 + j. Tile order [kt][mt(8)].
#define OFF_FLAG 0        // uint flag: 1 = inputs bf16, 0 = fp32
#define OFF_B0   16
#define OFF_B1   272
#define OFF_B2   528
#define OFF_B3   784
#define OFF_BSIG 1040
#define OFF_BRGB 1041
#define OFF_W0   1056     // K=64 (47 padded): 4 kt x 8 mt = 32 tiles * 512
#define OFF_W1   17440    // K=256: 16 kt x 8 mt = 128 tiles * 512
#define OFF_W2   82976
#define OFF_W3   148512
#define OFF_WH   214048   // head: 16 kt x 1 mt (cols rgb0,rgb1,rgb2,sig,0..)
#define OFF_PL   222240   // transposed planes [plane][pos(16384)][rank(8)]

__device__ __forceinline__ float bf2f(ushort_t u) {
  union { uint_t i; float f; } c; c.i = ((uint_t)u) << 16; return c.f;
}
__device__ __forceinline__ ushort_t f2bf(float f) {
  union { float f; uint_t i; } c; c.f = f;
  uint_t x = c.i;
  return (ushort_t)((x + 0x7fffu + ((x >> 16) & 1u)) >> 16);
}
__device__ __forceinline__ uint_t pk2bf(float a, float b) {
  __hip_bfloat162 h = __float22bfloat162_rn(float2{a, b});
  union { __hip_bfloat162 h; uint_t u; } c; c.h = h; return c.u;
}
__device__ __forceinline__ float ldf(const void* p, long i, int isbf) {
  return isbf ? bf2f(((const ushort_t*)p)[i]) : ((const float*)p)[i];
}
__device__ __forceinline__ ushort_t ldbf(const void* p, long i, int isbf) {
  return isbf ? ((const ushort_t*)p)[i] : f2bf(((const float*)p)[i]);
}
__device__ __forceinline__ void stf(void* p, long i, int isbf, float v) {
  if (isbf) ((ushort_t*)p)[i] = f2bf(v);
  else      ((float*)p)[i] = v;
}

// Activation LDS layout = 32x32x16 B-fragment native (128 points = 4 n-tiles):
// element (point p, col k) -> frag(ntile=p>>5, kt=k>>4), lane = ((k>>3)&1)*32
// + (p&31), j = k&7.  frag stride 512 ushorts, ntile stride 8192.
__device__ __forceinline__ int fragaddr(int p, int k) {
  return ((p >> 5) << 13) + ((k >> 4) << 9) + (((k >> 3) & 1) << 8)
       + ((p & 31) << 3) + (k & 7);
}

union U { uint4 u; bf16x8 v; };

// ------------------------------------------------------------------
__global__ void sniff_dtype(const void* __restrict__ f, ushort_t* __restrict__ ws) {
  __shared__ int s_cnt;
  if (threadIdx.x == 0) s_cnt = 0;
  __syncthreads();
  const ushort_t* u = (const ushort_t*)f;
  int c = 0;
  for (int j = 0; j < 4; ++j) {
    ushort_t v = u[(threadIdx.x * 4 + j) * 2];
    int e = (v >> 7) & 0xFF;
    if (e > 100 && e < 140) ++c;
  }
  atomicAdd(&s_cnt, c);
  __syncthreads();
  if (threadIdx.x == 0) ((uint_t*)ws)[0] = (s_cnt >= 160) ? 1u : 0u;
}

__global__ void prep_bias(const void* __restrict__ b0, const void* __restrict__ b1,
                          const void* __restrict__ b2, const void* __restrict__ b3,
                          const void* __restrict__ bsig, const void* __restrict__ brgb,
                          ushort_t* __restrict__ ws) {
  const int isbf = (int)((const uint_t*)ws)[0];
  int i = threadIdx.x;
  ws[OFF_B0 + i] = ldbf(b0, i, isbf);
  ws[OFF_B1 + i] = ldbf(b1, i, isbf);
  ws[OFF_B2 + i] = ldbf(b2, i, isbf);
  ws[OFF_B3 + i] = ldbf(b3, i, isbf);
  if (i == 0) ws[OFF_BSIG] = ldbf(bsig, 0, isbf);
  if (i < 3) ws[OFF_BRGB + i] = ldbf(brgb, i, isbf);
}

// weights -> 32x32x16 A-frags of W^T, tile order [kt][mt]
__global__ void prep_weights(const void* __restrict__ W0,
                             const void* __restrict__ W1,
                             const void* __restrict__ W2,
                             const void* __restrict__ W3,
                             const void* __restrict__ Wsig,
                             const void* __restrict__ Wrgb,
                             ushort_t* __restrict__ ws) {
  const int isbf = (int)((const uint_t*)ws)[0];
  int t = blockIdx.x * 256 + threadIdx.x;   // 432 tiles * 64 lanes = 27648
  if (t >= 432 * 64) return;
  int lane = t & 63;
  int tile = t >> 6;
  const void* src = nullptr;
  ushort_t* dst;
  int local, Ksrc = 256;
  bool head = false;
  if (tile < 32) { local = tile; src = W0; Ksrc = 47; dst = ws + OFF_W0 + (size_t)local * 512; }
  else if (tile < 160) { local = tile - 32;  src = W1; dst = ws + OFF_W1 + (size_t)local * 512; }
  else if (tile < 288) { local = tile - 160; src = W2; dst = ws + OFF_W2 + (size_t)local * 512; }
  else if (tile < 416) { local = tile - 288; src = W3; dst = ws + OFF_W3 + (size_t)local * 512; }
  else { local = tile - 416; head = true; dst = ws + OFF_WH + (size_t)local * 512; }
  int kt = head ? local : (local >> 3);
  int mt = head ? 0 : (local & 7);
  int n = mt * 32 + (lane & 31);         // out-col (A-frag m)
  int kb = kt * 16 + (lane >> 5) * 8;    // k base
  for (int j = 0; j < 8; ++j) {
    int k = kb + j;
    ushort_t v = 0;
    if (head) {
      if (n < 3) v = ldbf(Wrgb, (long)k * 3 + n, isbf);
      else if (n == 3) v = ldbf(Wsig, k, isbf);
    } else if (k < Ksrc) {
      v = ldbf(src, (long)k * 256 + n, isbf);
    }
    dst[lane * 8 + j] = v;
  }
}

__global__ void prep_planes(const void* __restrict__ fxy,
                            const void* __restrict__ fxz,
                            const void* __restrict__ fyz,
                            ushort_t* __restrict__ ws) {
  const int isbf = (int)((const uint_t*)ws)[0];
  int t = blockIdx.x * 256 + threadIdx.x;   // 3*16384 = 49152
  int plane = t >> 14, pos = t & 16383;
  const void* src = (plane == 0) ? fxy : (plane == 1) ? fxz : fyz;
  ushort_t* d = ws + OFF_PL + (size_t)plane * 131072 + (size_t)pos * 8;
  for (int r = 0; r < 8; ++r) d[r] = ldbf(src, (long)r * 16384 + pos, isbf);
}

// ------------------------------------------------------------------
// main: block = 256 thr / 4 waves / 128 points, 2 waves/SIMD (256 regs).
// Wave w: out-cols [w*64, w*64+64) (2 m-tiles) x all 128 points.
// acc[2][4] f32x16 = 128 AGPRs.
// Round-10 evidence: 42% MfmaUtil with ~40% of cycles unaccounted ->
// exposed L2 latency on the per-kt weight loads (1-kt lookahead = 256
// MFMA-cyc < contended L2 latency) + per-layer cold starts.
// This version: distance-3 A-prefetch via 4-slot rotation a[kt&3];
// the peeled last group prefetches the NEXT layer's tiles 0..2 into the
// rotation so no layer cold-starts; B (LDS) prefetch distance 1 with a
// peeled tail (no past-end reads -> clean waitcnt drain at barriers).
// Precondition: a[0..2] hold THIS layer's tiles 0,1,2.
// Postcondition: a[0..2] hold nextW's tiles 0,1,2.
// ------------------------------------------------------------------
template <int KT>
__device__ __forceinline__ void mlp_layer(ushort_t* s_act,
                                          const ushort_t* __restrict__ wsW,
                                          const ushort_t* __restrict__ nextW,
                                          const ushort_t* __restrict__ bias,
                                          int w, int lane, U (&a)[4][2]) {
  f32x16 acc[2][4] = {};
  const int p31 = lane & 31;
  const int q2 = lane >> 5;
  const ushort_t* bptr = s_act + lane * 8;                  // + d*8192 + kt*512
  const ushort_t* aptr = wsW + (w * 2) * 512 + lane * 8;    // + kt*4096 + mi*512
  const ushort_t* nptr = nextW + (w * 2) * 512 + lane * 8;
  U b[2][4];
#pragma unroll
  for (int d = 0; d < 4; ++d) b[0][d].u = *(const uint4*)(bptr + d * 8192);
  // main groups: kt = 0 .. KT-5
#pragma unroll 1
  for (int g = 0; g < KT / 4 - 1; ++g) {
    const ushort_t* ag = aptr + g * 16384;
    const ushort_t* bg = bptr + g * 2048;
#pragma unroll
    for (int j = 0; j < 4; ++j) {
      // prefetch A tile kt+3 -> slot (j+3)&3
#pragma unroll
      for (int mi = 0; mi < 2; ++mi)
        a[(j + 3) & 3][mi].u = *(const uint4*)(ag + (j + 3) * 4096 + mi * 512);
      // prefetch B kt+1 -> slot (j+1)&1
#pragma unroll
      for (int d = 0; d < 4; ++d)
        b[(j + 1) & 1][d].u = *(const uint4*)(bg + (j + 1) * 512 + d * 8192);
#pragma unroll
      for (int mi = 0; mi < 2; ++mi)
#pragma unroll
        for (int d = 0; d < 4; ++d)
          acc[mi][d] = __builtin_amdgcn_mfma_f32_32x32x16_bf16(a[j & 3][mi].v, b[j & 1][d].v, acc[mi][d], 0, 0, 0);
    }
  }
  // peeled last group: kt = KT-4 .. KT-1; A-prefetch switches to nextW
  {
    const ushort_t* ag = aptr + (KT / 4 - 1) * 16384;
    const ushort_t* bg = bptr + (KT / 4 - 1) * 2048;
#pragma unroll
    for (int j = 0; j < 4; ++j) {
      if (j == 0) {
#pragma unroll
        for (int mi = 0; mi < 2; ++mi)
          a[3][mi].u = *(const uint4*)(ag + 3 * 4096 + mi * 512);   // tile KT-1
      } else {
#pragma unroll
        for (int mi = 0; mi < 2; ++mi)
          a[j - 1][mi].u = *(const uint4*)(nptr + (j - 1) * 4096 + mi * 512);  // next tiles 0..2
      }
      if (j < 3) {
#pragma unroll
        for (int d = 0; d < 4; ++d)
          b[(j + 1) & 1][d].u = *(const uint4*)(bg + (j + 1) * 512 + d * 8192);
      }
#pragma unroll
      for (int mi = 0; mi < 2; ++mi)
#pragma unroll
        for (int d = 0; d < 4; ++d)
          acc[mi][d] = __builtin_amdgcn_mfma_f32_32x32x16_bf16(a[j & 3][mi].v, b[j & 1][d].v, acc[mi][d], 0, 0, 0);
    }
  }
  __syncthreads();   // all waves done reading act
  // D: lane -> point p31 (in n-tile d); reg quad rq = 4 consecutive cols
  // col = w*64 + mi*32 + rq*8 + q2*4 + {0..3}
  ushort_t* wbase = s_act + w * 2048 + p31 * 8 + q2 * 4;
#pragma unroll
  for (int mi = 0; mi < 2; ++mi) {
#pragma unroll
    for (int rq = 0; rq < 4; ++rq) {
      int col0 = w * 64 + mi * 32 + rq * 8 + q2 * 4;
      ushort4 bb = *(const ushort4*)(bias + col0);
      float bf0 = bf2f(bb.x), bf1 = bf2f(bb.y), bf2v = bf2f(bb.z), bf3 = bf2f(bb.w);
#pragma unroll
      for (int d = 0; d < 4; ++d) {
        const f32x16& A = acc[mi][d];
        float v0 = fmaxf(A[rq * 4 + 0] + bf0, 0.0f);
        float v1 = fmaxf(A[rq * 4 + 1] + bf1, 0.0f);
        float v2 = fmaxf(A[rq * 4 + 2] + bf2v, 0.0f);
        float v3 = fmaxf(A[rq * 4 + 3] + bf3, 0.0f);
        uint2 pk; pk.x = pk2bf(v0, v1); pk.y = pk2bf(v2, v3);
        *(uint2*)(wbase + d * 8192 + mi * 1024 + (rq >> 1) * 512 + (rq & 1) * 256) = pk;
      }
    }
  }
  __syncthreads();   // act ready for next layer
}

__global__ __launch_bounds__(256, 2)
void tensorf_main(const void* __restrict__ x,
                  const ushort_t* __restrict__ ws,
                  void* __restrict__ out) {
  __shared__ ushort_t s_act[4 * 16 * 512];   // 64 KB frag-native act (128 pts)
  const int isbf = (int)((const uint_t*)ws)[0];
  const int tid = threadIdx.x;
  const int lane = tid & 63;
  const int wid = tid >> 6;        // 0..3
  const int blk = blockIdx.x;

  // Issue layer-0 A-prefetch (tiles 0..2) FIRST: latency hides under Phase A.
  U a[4][2];
  {
    const ushort_t* a0 = ws + OFF_W0 + (wid * 2) * 512 + lane * 8;
#pragma unroll
    for (int t = 0; t < 3; ++t)
#pragma unroll
      for (int mi = 0; mi < 2; ++mi)
        a[t][mi].u = *(const uint4*)(a0 + t * 4096 + mi * 512);
  }

  // ---- Phase A: features + PE into frag layout, cols 0..63 ----
  // 2 threads per point: s=0 gather + x + pad + trig lvl 4,5; s=1 trig lvl 0..3
  {
    int pl = tid >> 1;            // 0..127
    int s = tid & 1;
    long p = (long)blk * 128 + pl;
    float x0 = ldf(x, p * 3 + 0, isbf);
    float x1 = ldf(x, p * 3 + 1, isbf);
    float x2 = ldf(x, p * 3 + 2, isbf);
    float fx[3] = { x0, x1, x2 };
    if (s == 0) {
      int ix = (int)(((x0 + 1.0f) * 0.5f) * 127.0f);
      int iy = (int)(((x1 + 1.0f) * 0.5f) * 127.0f);
      int iz = (int)(((x2 + 1.0f) * 0.5f) * 127.0f);
      ix = ix < 0 ? 0 : (ix > 127 ? 127 : ix);
      iy = iy < 0 ? 0 : (iy > 127 ? 127 : iy);
      iz = iz < 0 ? 0 : (iz > 127 ? 127 : iz);
      union { uint4 u; ushort_t s[8]; } a4, b4, c4;
      a4.u = *(const uint4*)(ws + OFF_PL + (size_t)(iy * 128 + ix) * 8);
      b4.u = *(const uint4*)(ws + OFF_PL + 131072 + (size_t)(iz * 128 + ix) * 8);
      c4.u = *(const uint4*)(ws + OFF_PL + 262144 + (size_t)(iz * 128 + iy) * 8);
      union { uint4 u; uint_t w[4]; } f;
#pragma unroll
      for (int r = 0; r < 8; r += 2) {
        float f0 = bf2f(a4.s[r]) + bf2f(b4.s[r]) + bf2f(c4.s[r]);
        float f1 = bf2f(a4.s[r + 1]) + bf2f(b4.s[r + 1]) + bf2f(c4.s[r + 1]);
        f.w[r >> 1] = pk2bf(f0, f1);
      }
      *(uint4*)(s_act + fragaddr(pl, 0)) = f.u;      // cols 0..7 contiguous
      *(uint_t*)(s_act + fragaddr(pl, 8)) = pk2bf(x0, x1);
      s_act[fragaddr(pl, 10)] = f2bf(x2);
#pragma unroll
      for (int l = 4; l < 6; ++l) {
        float fr = (float)(1 << l);
        int k0 = 11 + l * 6;
#pragma unroll
        for (int dd = 0; dd < 3; ++dd) {
          float ang = fx[dd] * fr;
          s_act[fragaddr(pl, k0 + dd)]     = f2bf(__sinf(ang));
          s_act[fragaddr(pl, k0 + 3 + dd)] = f2bf(__cosf(ang));
        }
      }
      s_act[fragaddr(pl, 47)] = 0;
      *(uint4*)(s_act + fragaddr(pl, 48)) = uint4{0, 0, 0, 0};
      *(uint4*)(s_act + fragaddr(pl, 56)) = uint4{0, 0, 0, 0};
    } else {
#pragma unroll
      for (int l = 0; l < 4; ++l) {
        float fr = (float)(1 << l);
        int k0 = 11 + l * 6;
#pragma unroll
        for (int dd = 0; dd < 3; ++dd) {
          float ang = fx[dd] * fr;
          s_act[fragaddr(pl, k0 + dd)]     = f2bf(__sinf(ang));
          s_act[fragaddr(pl, k0 + 3 + dd)] = f2bf(__cosf(ang));
        }
      }
    }
  }
  __syncthreads();

  mlp_layer<4>(s_act,  ws + OFF_W0, ws + OFF_W1, ws + OFF_B0, wid, lane, a);
  mlp_layer<16>(s_act, ws + OFF_W1, ws + OFF_W2, ws + OFF_B1, wid, lane, a);
  mlp_layer<16>(s_act, ws + OFF_W2, ws + OFF_W3, ws + OFF_B2, wid, lane, a);
  mlp_layer<16>(s_act, ws + OFF_W3, ws + OFF_WH, ws + OFF_B3, wid, lane, a);

  // ---- head: D = Wh^T(32x256, cols 0..3 real) x Act^T; wave w = n-tile w ----
  {
    f32x16 acc = {};
    const int p31 = lane & 31;
    const int q2 = lane >> 5;
    const ushort_t* hb = s_act + wid * 8192 + lane * 8;
    const ushort_t* wh = ws + OFF_WH + lane * 8;
#pragma unroll 4
    for (int kt = 0; kt < 16; ++kt) {
      union { uint4 u; bf16x8 v; } ta, tb;
      ta.u = *(const uint4*)(wh + kt * 512);
      tb.u = *(const uint4*)(hb + kt * 512);
      acc = __builtin_amdgcn_mfma_f32_32x32x16_bf16(ta.v, tb.v, acc, 0, 0, 0);
    }
    if (q2 == 0) {   // regs 0..3 = cols 0..3 = rgb0, rgb1, rgb2, sigma
      long pp = (long)blk * 128 + wid * 32 + p31;
      float br0 = bf2f(ws[OFF_BRGB + 0]), br1 = bf2f(ws[OFF_BRGB + 1]), br2 = bf2f(ws[OFF_BRGB + 2]);
      float bs = bf2f(ws[OFF_BSIG]);
      float z0 = acc[0] + br0, z1 = acc[1] + br1, z2 = acc[2] + br2;
      stf(out, pp * 3 + 0, isbf, 1.0f / (1.0f + __expf(-z0)));
      stf(out, pp * 3 + 1, isbf, 1.0f / (1.0f + __expf(-z1)));
      stf(out, pp * 3 + 2, isbf, 1.0f / (1.0f + __expf(-z2)));
      float zs = acc[3] + bs;
      float sp = (zs > 20.0f) ? zs : __logf(1.0f + __expf(zs));
      stf(out, (long)3 * NPTS + pp, isbf, sp);
    }
  }
}

extern "C" void kernel_launch(void* const* d_in, const int* in_sizes, int n_in,
                              void* d_out, int out_size, void* d_ws, size_t ws_size,
                              hipStream_t stream) {
  const void* x    = d_in[0];
  const void* fxy  = d_in[1];
  const void* fxz  = d_in[2];
  const void* fyz  = d_in[3];
  const void* W0   = d_in[4];
  const void* b0   = d_in[5];
  const void* W1   = d_in[6];
  const void* b1   = d_in[7];
  const void* W2   = d_in[8];
  const void* b2   = d_in[9];
  const void* W3   = d_in[10];
  const void* b3   = d_in[11];
  const void* Wsig = d_in[12];
  const void* bsig = d_in[13];
  const void* Wrgb = d_in[14];
  const void* brgb = d_in[15];
  ushort_t* ws = (ushort_t*)d_ws;

  hipLaunchKernelGGL(sniff_dtype, dim3(1), dim3(64), 0, stream, fxy, ws);
  hipLaunchKernelGGL(prep_bias, dim3(1), dim3(256), 0, stream,
                     b0, b1, b2, b3, bsig, brgb, ws);
  hipLaunchKernelGGL(prep_weights, dim3(108), dim3(256), 0, stream,
                     W0, W1, W2, W3, Wsig, Wrgb, ws);
  hipLaunchKernelGGL(prep_planes, dim3(192), dim3(256), 0, stream,
                     fxy, fxz, fyz, ws);
  hipLaunchKernelGGL(tensorf_main, dim3(8192), dim3(256), 0, stream,
                     x, ws, d_out);
}